// Round 7
// baseline (185.854 us; speedup 1.0000x reference)
//
#include <hip/hip_runtime.h>
#include <hip/hip_bf16.h>
#include <cstdint>
#include <cstddef>

// Problem constants
#define DIMN 1024
#define NHEAD 16
#define HDIM 64
#define NB 2
#define SEQ 2048
#define MROWS 4096           // NB*SEQ
#define BHN 32               // NB*NHEAD
#define QKV_STRIDE 4194304   // BHN*SEQ*HDIM (Q,K regions)
#define BH_ELEMS 131072      // SEQ*HDIM = 64*2048

// Q pre-scale: 1/sqrt(64) * log2(e), so attn uses a single v_exp_f32 per score.
#define QSCALE 0.18033688011112042f

typedef float f32x4 __attribute__((ext_vector_type(4)));
typedef __bf16 bf16x8 __attribute__((ext_vector_type(8)));

__device__ __forceinline__ void async_copy16(const void* g, void* l) {
    __builtin_amdgcn_global_load_lds(
        (__attribute__((address_space(1))) void*)(g),
        (__attribute__((address_space(3))) void*)(l), 16, 0, 0);
}

__device__ __forceinline__ unsigned short bf16_bits(float f) {
    __hip_bfloat16 hb = __float2bfloat16(f);
    return *(unsigned short*)&hb;
}

// raw v_exp_f32 (2^x). OCML exp2f adds subnormal fixup code (~4 VALU); the
// raw instruction is 1 op and handles -inf -> 0 correctly.
__device__ __forceinline__ float fast_exp2(float x) {
    return __builtin_amdgcn_exp2f(x);
}

// ---------------- fused prep: x->bf16, bias concat, W transposes ----------------
__global__ __launch_bounds__(256) void prep_kernel(
        const float* __restrict__ x, const float* __restrict__ bq,
        const float* __restrict__ bk, const float* __restrict__ bv,
        const float* __restrict__ Wq, const float* __restrict__ Wk,
        const float* __restrict__ Wv, const float* __restrict__ Wo,
        __hip_bfloat16* __restrict__ xbf, float* __restrict__ biasq,
        __hip_bfloat16* __restrict__ wqkvt, __hip_bfloat16* __restrict__ wot) {
    __shared__ float tile[32][33];
    const int bid = blockIdx.x;
    const int t = threadIdx.x;
    if (bid < 4096) {
        int i = (bid * 256 + t) * 4;
        float4 v = *(const float4*)(x + i);
        xbf[i + 0] = __float2bfloat16(v.x);
        xbf[i + 1] = __float2bfloat16(v.y);
        xbf[i + 2] = __float2bfloat16(v.z);
        xbf[i + 3] = __float2bfloat16(v.w);
    } else if (bid < 4099) {
        int base = (bid - 4096) * 1024 + t * 4;
#pragma unroll
        for (int e = 0; e < 4; e++) {
            int gi = base + e;
            int which = gi >> 10, off = gi & 1023;
            float v = (which == 0) ? bq[off] : (which == 1) ? bk[off] : bv[off];
            biasq[gi] = v;
        }
    } else {
        int rr = bid - 4099;
        int z = rr >> 10;                      // 0..3 -> Wq,Wk,Wv,Wo
        int tid = rr & 1023;
        int n0 = (tid & 31) * 32, k0 = (tid >> 5) * 32;
        const float* in = (z == 0) ? Wq : (z == 1) ? Wk : (z == 2) ? Wv : Wo;
        __hip_bfloat16* out = (z == 3) ? wot : wqkvt + (size_t)z * DIMN * DIMN;
        int tx = t & 31, ty = t >> 5;          // 32 x 8
#pragma unroll
        for (int r = 0; r < 32; r += 8)
            tile[ty + r][tx] = in[(size_t)(k0 + ty + r) * DIMN + n0 + tx];
        __syncthreads();
#pragma unroll
        for (int r = 0; r < 32; r += 8)
            out[(size_t)(n0 + ty + r) * DIMN + k0 + tx] =
                __float2bfloat16(tile[tx][ty + r]);
    }
}

// ---------------- QKV GEMM: 256^2 tile, ring-3, ONE barrier / K-tile ----------------
// grid 12x16 = 192 blocks, 512 threads (8 waves: 2M x 4N), per-wave 128x64 output.
// LDS 96 KB: A = 6 half-slots of 8 KB (slot = (tile%3)*2 + half), B same at +48 KB.
// Per K-tile t (BK=32): wait vmcnt(4), ONE raw s_barrier, then 12 ds_read_b128 +
// 4 global_load_lds (stage tile t+2) + 32 MFMA per wave in one region.
__global__ __launch_bounds__(512, 1) void gemm_qkv_kernel(
        const __hip_bfloat16* __restrict__ A, const __hip_bfloat16* __restrict__ Bt,
        const float* __restrict__ bias, __hip_bfloat16* __restrict__ qkv,
        __hip_bfloat16* __restrict__ vt) {
    __shared__ __align__(16) unsigned short SM[49152];   // 96 KB
    const int t = threadIdx.x;                 // 0..511
    const int m0 = blockIdx.y * 256;
    const int n0 = blockIdx.x * 256;
    const int lane = t & 63;
    const int w = t >> 6;
    const int wmid = w >> 2;                   // 0..1 (M)
    const int wnid = w & 3;                    // 0..3 (N)
    const int r16 = lane & 15;
    const int quad = lane >> 4;
    const int rsw = (quad ^ ((r16 >> 1) & 3)) * 8;   // swizzled read chunk (ushorts)
    const int blr0 = (wnid & 1) * 64;          // B local-row base within its half

    const int srow = t >> 2;
    const int scsw = (t & 3) ^ ((srow >> 1) & 3);
    const __hip_bfloat16* Ag = A + (size_t)(m0 + srow) * DIMN + scsw * 8;
    const __hip_bfloat16* Bg = Bt + (size_t)(n0 + srow) * DIMN + scsw * 8;

    f32x4 acc[8][4];
#pragma unroll
    for (int i = 0; i < 8; i++)
#pragma unroll
        for (int j = 0; j < 4; j++) acc[i][j] = (f32x4){0.f, 0.f, 0.f, 0.f};

    // prologue: stage tiles 0 (slot 0) and 1 (slot 1): A0,A1,B0,B1 each
#pragma unroll
    for (int tt = 0; tt < 2; tt++) {
#pragma unroll
        for (int h = 0; h < 2; h++)
            async_copy16(Ag + (size_t)h * 131072 + tt * 32,
                         (char*)(SM + (tt * 2 + h) * 4096 + t * 8));
#pragma unroll
        for (int h = 0; h < 2; h++)
            async_copy16(Bg + (size_t)h * 131072 + tt * 32,
                         (char*)(SM + 24576 + (tt * 2 + h) * 4096 + t * 8));
    }

    int sl = 0;                                // tile % 3
#pragma unroll 1
    for (int tt = 0; tt < 32; ++tt) {
        const int sl2 = (sl >= 1) ? (sl - 1) : 2;   // (tt+2) % 3
        if (tt == 31) {
            asm volatile("s_waitcnt vmcnt(0)" ::: "memory");
        } else {
            asm volatile("s_waitcnt vmcnt(4)" ::: "memory");
        }
        __builtin_amdgcn_s_barrier();

        const unsigned short* Asl = SM + (sl * 2 + wmid) * 4096;
        const unsigned short* Bsl = SM + 24576 + (sl * 2 + (wnid >> 1)) * 4096;

        // all fragment reads for the tile (12 x ds_read_b128)
        bf16x8 af[8], bfr[4];
#pragma unroll
        for (int i = 0; i < 8; i++)
            af[i] = *(const bf16x8*)&Asl[(i * 16 + r16) * 32 + rsw];
#pragma unroll
        for (int j = 0; j < 4; j++)
            bfr[j] = *(const bf16x8*)&Bsl[(blr0 + j * 16 + r16) * 32 + rsw];

        // stage tile tt+2 into slot sl2 (4 x global_load_lds; fly for 2 tiles)
        if (tt < 30) {
#pragma unroll
            for (int h = 0; h < 2; h++) {
                async_copy16(Ag + (size_t)h * 131072 + (tt + 2) * 32,
                             (char*)(SM + (sl2 * 2 + h) * 4096 + t * 8));
                async_copy16(Bg + (size_t)h * 131072 + (tt + 2) * 32,
                             (char*)(SM + 24576 + (sl2 * 2 + h) * 4096 + t * 8));
            }
        }

        // 32 MFMA, one cluster per barrier
        __builtin_amdgcn_s_setprio(1);
#pragma unroll
        for (int i = 0; i < 8; i++)
#pragma unroll
            for (int j = 0; j < 4; j++)
                acc[i][j] = __builtin_amdgcn_mfma_f32_16x16x32_bf16(
                    af[i], bfr[j], acc[i][j], 0, 0, 0);
        __builtin_amdgcn_s_setprio(0);

        sl = (sl < 2) ? (sl + 1) : 0;
    }

    // ---- epilogue (which is block-uniform: n0 is a multiple of 256)
    const int which = n0 >> 10;
#pragma unroll
    for (int j = 0; j < 4; j++) {
        const int n = n0 + wnid * 64 + j * 16 + r16;
        const float bv = bias[n];
        const int rem = n & 1023;
        const int h = rem >> 6, d = rem & 63;
#pragma unroll
        for (int i = 0; i < 8; i++) {
            const int mbase = m0 + wmid * 128 + i * 16 + quad * 4;
            const int b = mbase >> 11;
            const int lrow = mbase & 2047;
            const int bh = b * NHEAD + h;
            if (which == 2) {
                ushort4 pk;
                pk.x = bf16_bits(acc[i][j][0] + bv);
                pk.y = bf16_bits(acc[i][j][1] + bv);
                pk.z = bf16_bits(acc[i][j][2] + bv);
                pk.w = bf16_bits(acc[i][j][3] + bv);
                *(ushort4*)(vt + (size_t)bh * BH_ELEMS + (size_t)d * SEQ + lrow) = pk;
            } else {
#pragma unroll
                for (int r = 0; r < 4; r++) {
                    float v = acc[i][j][r] + bv;
                    if (which == 0) v *= QSCALE;   // fold 1/sqrt(hd)*log2e into Q
                    qkv[(size_t)which * QKV_STRIDE + (size_t)bh * BH_ELEMS +
                        (size_t)(lrow + r) * 64 + d] = __float2bfloat16(v);
                }
            }
        }
    }
}

// ---------------- output GEMM: 64x128 tiles (512 blocks, 2/CU), BK=32 ----------------
__global__ __launch_bounds__(256) void gemm_out_kernel(
        const __hip_bfloat16* __restrict__ A, const __hip_bfloat16* __restrict__ Bt,
        const float* __restrict__ bias, float* __restrict__ outp) {
    __shared__ __align__(16) unsigned short As[64 * 32];
    __shared__ __align__(16) unsigned short Bs[128 * 32];
    const int t = threadIdx.x;
    const int m0 = blockIdx.y * 64;
    const int n0 = blockIdx.x * 128;
    const int lane = t & 63;
    const int w = t >> 6;
    const int wm = (w >> 1) * 32;
    const int wn = (w & 1) * 64;
    const int r16 = lane & 15;
    const int quad = lane >> 4;

    f32x4 acc[2][4];
#pragma unroll
    for (int i = 0; i < 2; i++)
#pragma unroll
        for (int j = 0; j < 4; j++) acc[i][j] = (f32x4){0.f, 0.f, 0.f, 0.f};

    const int rowA = t >> 2;
    const int kch = (t & 3) * 8;

    for (int k0 = 0; k0 < DIMN; k0 += 32) {
        __syncthreads();
        async_copy16(A + (size_t)(m0 + rowA) * DIMN + k0 + kch, (char*)As + t * 16);
#pragma unroll
        for (int r = 0; r < 2; r++) {
            int row = rowA + r * 64;
            async_copy16(Bt + (size_t)(n0 + row) * DIMN + k0 + kch,
                         (char*)Bs + (size_t)(row * 4 + (t & 3)) * 16);
        }
        __syncthreads();

        bf16x8 af[2], bfr[4];
#pragma unroll
        for (int i = 0; i < 2; i++)
            af[i] = *(const bf16x8*)&As[(wm + i * 16 + r16) * 32 + quad * 8];
#pragma unroll
        for (int j = 0; j < 4; j++)
            bfr[j] = *(const bf16x8*)&Bs[(wn + j * 16 + r16) * 32 + quad * 8];
#pragma unroll
        for (int i = 0; i < 2; i++)
#pragma unroll
            for (int j = 0; j < 4; j++)
                acc[i][j] = __builtin_amdgcn_mfma_f32_16x16x32_bf16(
                    af[i], bfr[j], acc[i][j], 0, 0, 0);
    }

#pragma unroll
    for (int i = 0; i < 2; i++)
#pragma unroll
        for (int j = 0; j < 4; j++) {
            int n = n0 + wn + j * 16 + r16;
            float bv = bias[n];
#pragma unroll
            for (int r = 0; r < 4; r++) {
                int m = m0 + wm + i * 16 + quad * 4 + r;
                outp[(size_t)m * DIMN + n] = acc[i][j][r] + bv;
            }
        }
}

// ---------------- MFMA flash attention, single-barrier deep pipeline ----------------
// Lazy quiet softmax: out = sum(exp(s)V) / (exp(max_s) + sum(exp(s))).
// Q pre-scaled by log2e; each score's exp is ONE v_exp_f32.
// grid 512 blocks, 512 threads (8 waves): 4 q-subtiles x 2 k-halves.
// WORK-BALANCED block decode: block pair (2c, 2c+1) = (qt=ph, qt=15-ph) with the
// SAME bh -> every adjacent pair sums to 17 work-units (was: first 256 blocks
// all-heavy, last 256 all-light -> heavy CUs ran ~31 units while light CUs sat
// idle at ~9; ~45% CU-time wasted). Pair also shares K/V stream in L2.
// LDS 72KB: Kdbuf 2x16KB (0..32767) | Vdbuf 2x16KB (32768..65535) | Ps 8KB.
// ONE barrier per k-tile: prefetches for tile i+1 issued right after the
// barrier drain a full iteration later.
__global__ __launch_bounds__(512, 4) void attn_mfma_kernel(
        const __hip_bfloat16* __restrict__ qkv, const __hip_bfloat16* __restrict__ vt,
        __hip_bfloat16* __restrict__ ctxout) {
    __shared__ __align__(16) unsigned short SMEM[36864];   // 72 KB

    const int bx = blockIdx.x;
    const int pr = bx >> 1;                    // 0..255
    const int bh = pr & 31;
    const int ph = pr >> 5;                    // 0..7
    const int qt = (bx & 1) ? (15 - ph) : ph;  // balanced heavy/light pairing
    const int t = threadIdx.x;                 // 0..511
    const int lane = t & 63;
    const int w = t >> 6;                      // 0..7
    const int half = w >> 2;                   // k-half
    const int wq = w & 3;                      // q-subtile
    const int r16 = lane & 15;
    const int quad = lane >> 4;
    const int qbase = qt * 128 + wq * 32;
    const int swz = quad ^ ((r16 >> 1) & 3);   // K/V read chunk swizzle
    const int pkey = (r16 >> 1) & 3;           // Ps chunk swizzle key

    const __hip_bfloat16* Qg = qkv + (size_t)bh * BH_ELEMS;
    const __hip_bfloat16* Kg = qkv + (size_t)QKV_STRIDE + (size_t)bh * BH_ELEMS;
    const __hip_bfloat16* Vtg = vt + (size_t)bh * BH_ELEMS;   // [d][seq]

    unsigned short* PsW = SMEM + 32768 + w * 512;  // 1KB/wave: [16 q][32 k] swizzled

    // staging chunk decomposition (chunk id cb = t&511 of a 512-chunk tile-pair)
    const int cb_kp = (t & 511) >> 8;
    const int cb_rr = ((t & 511) >> 2) & 63;
    const int cb_cg = ((t & 511) & 3) ^ ((cb_rr >> 1) & 3);

    bf16x8 bq[2][2];
#pragma unroll
    for (int ng = 0; ng < 2; ng++)
#pragma unroll
        for (int kp = 0; kp < 2; kp++)
            bq[ng][kp] = *(const bf16x8*)(Qg + (size_t)(qbase + ng * 16 + r16) * 64 +
                                          kp * 32 + quad * 8);

    f32x4 oT[4][2];
#pragma unroll
    for (int mt = 0; mt < 4; mt++)
#pragma unroll
        for (int ng = 0; ng < 2; ng++) oT[mt][ng] = (f32x4){0.f, 0.f, 0.f, 0.f};
    float m_run[2] = {-1e30f, -1e30f};
    float z_run[2] = {0.f, 0.f};

    const int niter = qt + 1;

    // prologue: stage K(0) and V(0) (tiles 0 and qt+1) into buffer 0 of each dbuf
#pragma unroll
    for (int it = 0; it < 2; it++) {
        int cl = it * 512 + t;
        int ktile = (cl >> 9) ? (qt + 1) : 0;
        async_copy16(Kg + (size_t)(ktile * 64 + cb_rr) * 64 + cb_kp * 32 + cb_cg * 8,
                     (char*)SMEM + (size_t)cl * 16);
        async_copy16(Vtg + (size_t)cb_rr * SEQ + ktile * 64 + cb_kp * 32 + cb_cg * 8,
                     (char*)SMEM + 32768 + (size_t)cl * 16);
    }

#pragma unroll 1
    for (int i = 0; i < niter; i++) {
        const int curb = i & 1;
        __syncthreads();   // K(i),V(i) landed; all waves done with K(i-1),V(i-1)

        // prefetch K(i+1),V(i+1) into the other buffers (consumed next iter)
        if (i + 1 < niter) {
            int ktA = i + 1;
            int ktB = qt + 2 + i; if (ktB > 31) ktB = 31;   // defensive clamp
#pragma unroll
            for (int it = 0; it < 2; it++) {
                int cl = it * 512 + t;
                int ktile = (cl >> 9) ? ktB : ktA;
                async_copy16(Kg + (size_t)(ktile * 64 + cb_rr) * 64 + cb_kp * 32 + cb_cg * 8,
                             (char*)SMEM + (size_t)(curb ^ 1) * 16384 + (size_t)cl * 16);
                async_copy16(Vtg + (size_t)cb_rr * SEQ + ktile * 64 + cb_kp * 32 + cb_cg * 8,
                             (char*)SMEM + 32768 + (size_t)(curb ^ 1) * 16384 + (size_t)cl * 16);
            }
        }

        const int ktile = half ? (qt + 1 + i) : i;
        const bool active = (ktile * 64 <= qbase + 31);

        if (active) {
            const unsigned short* KsW = SMEM + curb * 8192 + half * 4096;  // ushort offs
            f32x4 st[4][2];
#pragma unroll
            for (int mt = 0; mt < 4; mt++)
#pragma unroll
                for (int ng = 0; ng < 2; ng++) st[mt][ng] = (f32x4){0.f, 0.f, 0.f, 0.f};
#pragma unroll
            for (int mt = 0; mt < 4; mt++)
#pragma unroll
                for (int kp = 0; kp < 2; kp++) {
                    bf16x8 ak = *(const bf16x8*)&KsW[kp * 2048 + (mt * 16 + r16) * 32 + swz * 8];
                    st[mt][0] = __builtin_amdgcn_mfma_f32_16x16x32_bf16(ak, bq[0][kp], st[mt][0], 0, 0, 0);
                    st[mt][1] = __builtin_amdgcn_mfma_f32_16x16x32_bf16(ak, bq[1][kp], st[mt][1], 0, 0, 0);
                }

            // causal mask (diagonal-straddling tiles only; wave-uniform branch)
            if (ktile * 64 + 63 > qbase) {
#pragma unroll
                for (int mt = 0; mt < 4; mt++) {
                    int kb = ktile * 64 + mt * 16 + quad * 4;
#pragma unroll
                    for (int ng = 0; ng < 2; ng++) {
                        int q = qbase + ng * 16 + r16;
#pragma unroll
                        for (int r = 0; r < 4; r++)
                            if (kb + r > q) st[mt][ng][r] = -__builtin_inff();
                    }
                }
            }

            // unshifted exp2 via raw v_exp_f32; st becomes P; m,z per lane
#pragma unroll
            for (int mt = 0; mt < 4; mt++)
#pragma unroll
                for (int ng = 0; ng < 2; ng++) {
                    float s0 = st[mt][ng][0], s1 = st[mt][ng][1];
                    float s2 = st[mt][ng][2], s3 = st[mt][ng][3];
                    m_run[ng] = fmaxf(m_run[ng], fmaxf(fmaxf(s0, s1), fmaxf(s2, s3)));
                    float p0 = fast_exp2(s0), p1 = fast_exp2(s1);
                    float p2 = fast_exp2(s2), p3 = fast_exp2(s3);
                    z_run[ng] += (p0 + p1) + (p2 + p3);
                    st[mt][ng][0] = p0; st[mt][ng][1] = p1;
                    st[mt][ng][2] = p2; st[mt][ng][3] = p3;
                }

            const unsigned short* VsW = SMEM + 16384 + curb * 8192 + half * 4096;
            // 4 phases: (k-half p) x (q-group ng): pack P into 1KB Ps, then PV.
#pragma unroll
            for (int p = 0; p < 2; p++) {
#pragma unroll
                for (int ng = 0; ng < 2; ng++) {
#pragma unroll
                    for (int ml = 0; ml < 2; ml++) {
                        int mt = p * 2 + ml;
                        ushort4 pk;
                        pk.x = bf16_bits(st[mt][ng][0]);
                        pk.y = bf16_bits(st[mt][ng][1]);
                        pk.z = bf16_bits(st[mt][ng][2]);
                        pk.w = bf16_bits(st[mt][ng][3]);
                        int c = (ml * 2 + (quad >> 1)) ^ pkey;
                        *(ushort4*)&PsW[r16 * 32 + c * 8 + (quad & 1) * 4] = pk;
                    }
                    bf16x8 bp = *(const bf16x8*)&PsW[r16 * 32 + (quad ^ pkey) * 8];
#pragma unroll
                    for (int mt = 0; mt < 4; mt++) {
                        bf16x8 av = *(const bf16x8*)&VsW[p * 2048 + (mt * 16 + r16) * 32 + swz * 8];
                        oT[mt][ng] = __builtin_amdgcn_mfma_f32_16x16x32_bf16(
                            av, bp, oT[mt][ng], 0, 0, 0);
                    }
                }
            }
        }
    }

    // fold per-lane m,z across quads
#pragma unroll
    for (int off = 16; off < 64; off <<= 1)
#pragma unroll
        for (int ng = 0; ng < 2; ng++) {
            m_run[ng] = fmaxf(m_run[ng], __shfl_xor(m_run[ng], off, 64));
            z_run[ng] += __shfl_xor(z_run[ng], off, 64);
        }

    // ---- combine k-halves through LDS (K/V and Ps regions dead) ----
    __syncthreads();
    f32x4* CbO = (f32x4*)SMEM;                        // 32KB
    f32x4* Ml = (f32x4*)((char*)SMEM + 32768);        // 4KB
    if (w >= 4) {
        int w4 = w - 4;
#pragma unroll
        for (int mt = 0; mt < 4; mt++)
#pragma unroll
            for (int ng = 0; ng < 2; ng++)
                CbO[((w4 * 8 + mt * 2 + ng) << 6) + lane] = oT[mt][ng];
        f32x4 ml;
        ml[0] = m_run[0]; ml[1] = m_run[1]; ml[2] = z_run[0]; ml[3] = z_run[1];
        Ml[(w4 << 6) + lane] = ml;
    }
    __syncthreads();
    if (w < 4) {
        f32x4 ml = Ml[(w << 6) + lane];
        float rd[2];
#pragma unroll
        for (int ng = 0; ng < 2; ng++) {
            float mtot = fmaxf(m_run[ng], ml[ng]);
            float ztot = z_run[ng] + ml[2 + ng];
            rd[ng] = 1.f / (fast_exp2(mtot) + ztot);  // quiet softmax denominator
        }
        const int b = bh >> 4, h = bh & 15;
#pragma unroll
        for (int mt = 0; mt < 4; mt++)
#pragma unroll
            for (int ng = 0; ng < 2; ng++) {
                f32x4 O1 = CbO[((w * 8 + mt * 2 + ng) << 6) + lane];
                int q = qbase + ng * 16 + r16;
                ushort4 pk;
                pk.x = bf16_bits((oT[mt][ng][0] + O1[0]) * rd[ng]);
                pk.y = bf16_bits((oT[mt][ng][1] + O1[1]) * rd[ng]);
                pk.z = bf16_bits((oT[mt][ng][2] + O1[2]) * rd[ng]);
                pk.w = bf16_bits((oT[mt][ng][3] + O1[3]) * rd[ng]);
                *(ushort4*)(ctxout + ((size_t)(b * SEQ + q)) * DIMN + h * 64 +
                            mt * 16 + quad * 4) = pk;
            }
    }
}

// ---------------- launch ----------------

extern "C" void kernel_launch(void* const* d_in, const int* in_sizes, int n_in,
                              void* d_out, int out_size, void* d_ws, size_t ws_size,
                              hipStream_t stream) {
    const float* x  = (const float*)d_in[0];
    const float* Wq = (const float*)d_in[1];
    const float* bq = (const float*)d_in[2];
    const float* Wk = (const float*)d_in[3];
    const float* bk = (const float*)d_in[4];
    const float* Wv = (const float*)d_in[5];
    const float* bv = (const float*)d_in[6];
    const float* Wo = (const float*)d_in[7];
    const float* bo = (const float*)d_in[8];

    char* ws = (char*)d_ws;
    __hip_bfloat16* xbf   = (__hip_bfloat16*)(ws);                           // 8 MB
    __hip_bfloat16* wqkvt = (__hip_bfloat16*)(ws + (8u << 20));              // 6 MB
    __hip_bfloat16* wot   = (__hip_bfloat16*)(ws + (14u << 20));             // 2 MB
    float*          biasq = (float*)(ws + (16u << 20));                      // 12 KB (pad 64K)
    __hip_bfloat16* qkv   = (__hip_bfloat16*)(ws + (16u << 20) + 65536u);    // 16 MB (Q,K)
    __hip_bfloat16* vt    = (__hip_bfloat16*)(ws + (16u << 20) + 65536u + (16u << 20)); // 8 MB
    __hip_bfloat16* ctx   = (__hip_bfloat16*)(ws + (16u << 20) + 65536u + (24u << 20)); // 8 MB
    float* out = (float*)d_out;

    prep_kernel<<<8195, 256, 0, stream>>>(x, bq, bk, bv, Wq, Wk, Wv, Wo,
                                          xbf, biasq, wqkvt, wot);
    gemm_qkv_kernel<<<dim3(12, 16), 512, 0, stream>>>(xbf, wqkvt, biasq, qkv, vt);
    attn_mfma_kernel<<<512, 512, 0, stream>>>(qkv, vt, ctx);
    gemm_out_kernel<<<dim3(8, 64), 256, 0, stream>>>(ctx, wot, bo, out);
}

// Round 10
// 172.370 us; speedup vs baseline: 1.0782x; 1.0782x over previous
//
#include <hip/hip_runtime.h>
#include <hip/hip_bf16.h>
#include <cstdint>
#include <cstddef>

// Problem constants
#define DIMN 1024
#define NHEAD 16
#define HDIM 64
#define NB 2
#define SEQ 2048
#define MROWS 4096           // NB*SEQ
#define BHN 32               // NB*NHEAD
#define QKV_STRIDE 4194304   // BHN*SEQ*HDIM (Q,K regions)
#define BH_ELEMS 131072      // SEQ*HDIM = 64*2048

// Q pre-scale: 1/sqrt(64) * log2(e), so attn uses a single v_exp_f32 per score.
#define QSCALE 0.18033688011112042f

typedef float f32x4 __attribute__((ext_vector_type(4)));
typedef __bf16 bf16x8 __attribute__((ext_vector_type(8)));

__device__ __forceinline__ void async_copy16(const void* g, void* l) {
    __builtin_amdgcn_global_load_lds(
        (__attribute__((address_space(1))) void*)(g),
        (__attribute__((address_space(3))) void*)(l), 16, 0, 0);
}

__device__ __forceinline__ unsigned short bf16_bits(float f) {
    __hip_bfloat16 hb = __float2bfloat16(f);
    return *(unsigned short*)&hb;
}

// raw v_exp_f32 (2^x). OCML exp2f adds subnormal fixup code (~4 VALU); the
// raw instruction is 1 op and handles -inf -> 0 correctly.
__device__ __forceinline__ float fast_exp2(float x) {
    return __builtin_amdgcn_exp2f(x);
}

// ---------------- fused prep: x->bf16, bias concat, W transposes ----------------
__global__ __launch_bounds__(256) void prep_kernel(
        const float* __restrict__ x, const float* __restrict__ bq,
        const float* __restrict__ bk, const float* __restrict__ bv,
        const float* __restrict__ Wq, const float* __restrict__ Wk,
        const float* __restrict__ Wv, const float* __restrict__ Wo,
        __hip_bfloat16* __restrict__ xbf, float* __restrict__ biasq,
        __hip_bfloat16* __restrict__ wqkvt, __hip_bfloat16* __restrict__ wot) {
    __shared__ float tile[32][33];
    const int bid = blockIdx.x;
    const int t = threadIdx.x;
    if (bid < 4096) {
        int i = (bid * 256 + t) * 4;
        float4 v = *(const float4*)(x + i);
        xbf[i + 0] = __float2bfloat16(v.x);
        xbf[i + 1] = __float2bfloat16(v.y);
        xbf[i + 2] = __float2bfloat16(v.z);
        xbf[i + 3] = __float2bfloat16(v.w);
    } else if (bid < 4099) {
        int base = (bid - 4096) * 1024 + t * 4;
#pragma unroll
        for (int e = 0; e < 4; e++) {
            int gi = base + e;
            int which = gi >> 10, off = gi & 1023;
            float v = (which == 0) ? bq[off] : (which == 1) ? bk[off] : bv[off];
            biasq[gi] = v;
        }
    } else {
        int rr = bid - 4099;
        int z = rr >> 10;                      // 0..3 -> Wq,Wk,Wv,Wo
        int tid = rr & 1023;
        int n0 = (tid & 31) * 32, k0 = (tid >> 5) * 32;
        const float* in = (z == 0) ? Wq : (z == 1) ? Wk : (z == 2) ? Wv : Wo;
        __hip_bfloat16* out = (z == 3) ? wot : wqkvt + (size_t)z * DIMN * DIMN;
        int tx = t & 31, ty = t >> 5;          // 32 x 8
#pragma unroll
        for (int r = 0; r < 32; r += 8)
            tile[ty + r][tx] = in[(size_t)(k0 + ty + r) * DIMN + n0 + tx];
        __syncthreads();
#pragma unroll
        for (int r = 0; r < 32; r += 8)
            out[(size_t)(n0 + ty + r) * DIMN + k0 + tx] =
                __float2bfloat16(tile[tx][ty + r]);
    }
}

// ---------------- QKV GEMM: 256x192 tile, ring-3, ONE barrier / K-tile ----------------
// grid 16x16 = 256 blocks -> ONE block on EVERY CU (the 256^2/192-block config
// left 64 CUs idle). 512 threads (8 waves: 2M x 4N), per-wave 128x48 output,
// 24 MFMA per wave per K-tile (total MFMA count unchanged vs 256^2).
// LDS 84 KB: A = 3 slots x 2 halves x 8 KB (48 KB), B = 3 slots x 12 KB (36 KB).
// B staging per tile: rows 0-127 by all 512 threads, rows 128-191 by waves 0-3
// only (wave-uniform) -> per-wave vmcnt per tile = 4 (w<4) or 3 (w>=4); the
// tile-top counted wait branches on wave id accordingly (vmcnt is per-wave, so
// divergent counts are self-consistent; a longer-than-needed wait is safe).
// Ring-3: stage tile t+2 while computing t; only tile t+1's batch in flight at
// the wait. Per-acc K accumulation order unchanged -> output bit-identical.
__global__ __launch_bounds__(512, 1) void gemm_qkv_kernel(
        const __hip_bfloat16* __restrict__ A, const __hip_bfloat16* __restrict__ Bt,
        const float* __restrict__ bias, __hip_bfloat16* __restrict__ qkv,
        __hip_bfloat16* __restrict__ vt) {
    __shared__ __align__(16) unsigned short SM[43008];   // 84 KB: A 48KB | B 36KB
    const int t = threadIdx.x;                 // 0..511
    const int m0 = blockIdx.y * 256;
    const int n0 = blockIdx.x * 192;
    const int lane = t & 63;
    const int w = t >> 6;
    const int wmid = w >> 2;                   // 0..1 (M)
    const int wnid = w & 3;                    // 0..3 (N)
    const int r16 = lane & 15;
    const int quad = lane >> 4;
    const int rsw = (quad ^ ((r16 >> 1) & 3)) * 8;   // swizzled read chunk (ushorts)
    const bool bstage2 = (w < 4);              // wave-uniform B second-instruction

    const int srow = t >> 2;                   // 0..127
    const int scsw = (t & 3) ^ ((srow >> 1) & 3);
    const __hip_bfloat16* Ag  = A  + (size_t)(m0 + srow) * DIMN + scsw * 8;
    const __hip_bfloat16* Bg1 = Bt + (size_t)(n0 + srow) * DIMN + scsw * 8;
    const __hip_bfloat16* Bg2 = Bt + (size_t)(n0 + 128 + srow) * DIMN + scsw * 8;

    f32x4 acc[8][3];
#pragma unroll
    for (int i = 0; i < 8; i++)
#pragma unroll
        for (int j = 0; j < 3; j++) acc[i][j] = (f32x4){0.f, 0.f, 0.f, 0.f};

    // prologue: stage tiles 0 (slot 0) and 1 (slot 1)
#pragma unroll
    for (int tt = 0; tt < 2; tt++) {
#pragma unroll
        for (int h = 0; h < 2; h++)
            async_copy16(Ag + (size_t)h * 131072 + tt * 32,
                         (char*)(SM + (tt * 2 + h) * 4096 + t * 8));
        async_copy16(Bg1 + tt * 32, (char*)(SM + 24576 + tt * 6144 + t * 8));
        if (bstage2)
            async_copy16(Bg2 + tt * 32,
                         (char*)(SM + 24576 + tt * 6144 + 4096 + t * 8));
    }

    int sl = 0;                                // tile % 3
#pragma unroll 1
    for (int tt = 0; tt < 32; ++tt) {
        const int sl2 = (sl >= 1) ? (sl - 1) : 2;   // (tt+2) % 3
        // tile-top wait: tile tt landed; allow tile tt+1's batch in flight
        if (tt == 31) {
            asm volatile("s_waitcnt vmcnt(0)" ::: "memory");
        } else if (bstage2) {
            asm volatile("s_waitcnt vmcnt(4)" ::: "memory");
        } else {
            asm volatile("s_waitcnt vmcnt(3)" ::: "memory");
        }
        __builtin_amdgcn_s_barrier();

        const unsigned short* Asl = SM + (sl * 2 + wmid) * 4096;
        const unsigned short* Bsl = SM + 24576 + sl * 6144;

        // all fragment reads for the tile (11 x ds_read_b128)
        bf16x8 af[8], bfr[3];
#pragma unroll
        for (int i = 0; i < 8; i++)
            af[i] = *(const bf16x8*)&Asl[(i * 16 + r16) * 32 + rsw];
#pragma unroll
        for (int j = 0; j < 3; j++)
            bfr[j] = *(const bf16x8*)&Bsl[(wnid * 48 + j * 16 + r16) * 32 + rsw];

        // stage tile tt+2 into slot sl2
        if (tt < 30) {
#pragma unroll
            for (int h = 0; h < 2; h++)
                async_copy16(Ag + (size_t)h * 131072 + (tt + 2) * 32,
                             (char*)(SM + (sl2 * 2 + h) * 4096 + t * 8));
            async_copy16(Bg1 + (tt + 2) * 32,
                         (char*)(SM + 24576 + sl2 * 6144 + t * 8));
            if (bstage2)
                async_copy16(Bg2 + (tt + 2) * 32,
                             (char*)(SM + 24576 + sl2 * 6144 + 4096 + t * 8));
        }

        // 24 MFMA, one cluster per barrier
        __builtin_amdgcn_s_setprio(1);
#pragma unroll
        for (int i = 0; i < 8; i++)
#pragma unroll
            for (int j = 0; j < 3; j++)
                acc[i][j] = __builtin_amdgcn_mfma_f32_16x16x32_bf16(
                    af[i], bfr[j], acc[i][j], 0, 0, 0);
        __builtin_amdgcn_s_setprio(0);

        sl = (sl < 2) ? (sl + 1) : 0;
    }

    // ---- epilogue ('which' is per-fragment uniform: nb is 16-aligned and
    // region boundaries are multiples of 1024)
#pragma unroll
    for (int j = 0; j < 3; j++) {
        const int nb = n0 + wnid * 48 + j * 16;
        const int n = nb + r16;
        const float bv = bias[n];
        const int which = nb >> 10;
        const int rem = n & 1023;
        const int hh = rem >> 6, d = rem & 63;
#pragma unroll
        for (int i = 0; i < 8; i++) {
            const int mbase = m0 + wmid * 128 + i * 16 + quad * 4;
            const int b = mbase >> 11;
            const int lrow = mbase & 2047;
            const int bh = b * NHEAD + hh;
            if (which == 2) {
                ushort4 pk;
                pk.x = bf16_bits(acc[i][j][0] + bv);
                pk.y = bf16_bits(acc[i][j][1] + bv);
                pk.z = bf16_bits(acc[i][j][2] + bv);
                pk.w = bf16_bits(acc[i][j][3] + bv);
                *(ushort4*)(vt + (size_t)bh * BH_ELEMS + (size_t)d * SEQ + lrow) = pk;
            } else {
#pragma unroll
                for (int r = 0; r < 4; r++) {
                    float v = acc[i][j][r] + bv;
                    if (which == 0) v *= QSCALE;   // fold 1/sqrt(hd)*log2e into Q
                    qkv[(size_t)which * QKV_STRIDE + (size_t)bh * BH_ELEMS +
                        (size_t)(lrow + r) * 64 + d] = __float2bfloat16(v);
                }
            }
        }
    }
}

// ---------------- output GEMM: 64x128 tiles (512 blocks, 2/CU), BK=32 ----------------
__global__ __launch_bounds__(256) void gemm_out_kernel(
        const __hip_bfloat16* __restrict__ A, const __hip_bfloat16* __restrict__ Bt,
        const float* __restrict__ bias, float* __restrict__ outp) {
    __shared__ __align__(16) unsigned short As[64 * 32];
    __shared__ __align__(16) unsigned short Bs[128 * 32];
    const int t = threadIdx.x;
    const int m0 = blockIdx.y * 64;
    const int n0 = blockIdx.x * 128;
    const int lane = t & 63;
    const int w = t >> 6;
    const int wm = (w >> 1) * 32;
    const int wn = (w & 1) * 64;
    const int r16 = lane & 15;
    const int quad = lane >> 4;

    f32x4 acc[2][4];
#pragma unroll
    for (int i = 0; i < 2; i++)
#pragma unroll
        for (int j = 0; j < 4; j++) acc[i][j] = (f32x4){0.f, 0.f, 0.f, 0.f};

    const int rowA = t >> 2;
    const int kch = (t & 3) * 8;

    for (int k0 = 0; k0 < DIMN; k0 += 32) {
        __syncthreads();
        async_copy16(A + (size_t)(m0 + rowA) * DIMN + k0 + kch, (char*)As + t * 16);
#pragma unroll
        for (int r = 0; r < 2; r++) {
            int row = rowA + r * 64;
            async_copy16(Bt + (size_t)(n0 + row) * DIMN + k0 + kch,
                         (char*)Bs + (size_t)(row * 4 + (t & 3)) * 16);
        }
        __syncthreads();

        bf16x8 af[2], bfr[4];
#pragma unroll
        for (int i = 0; i < 2; i++)
            af[i] = *(const bf16x8*)&As[(wm + i * 16 + r16) * 32 + quad * 8];
#pragma unroll
        for (int j = 0; j < 4; j++)
            bfr[j] = *(const bf16x8*)&Bs[(wn + j * 16 + r16) * 32 + quad * 8];
#pragma unroll
        for (int i = 0; i < 2; i++)
#pragma unroll
            for (int j = 0; j < 4; j++)
                acc[i][j] = __builtin_amdgcn_mfma_f32_16x16x32_bf16(
                    af[i], bfr[j], acc[i][j], 0, 0, 0);
    }

#pragma unroll
    for (int i = 0; i < 2; i++)
#pragma unroll
        for (int j = 0; j < 4; j++) {
            int n = n0 + wn + j * 16 + r16;
            float bv = bias[n];
#pragma unroll
            for (int r = 0; r < 4; r++) {
                int m = m0 + wm + i * 16 + quad * 4 + r;
                outp[(size_t)m * DIMN + n] = acc[i][j][r] + bv;
            }
        }
}

// ---------------- MFMA flash attention, single-barrier deep pipeline ----------------
// Lazy quiet softmax: out = sum(exp(s)V) / (exp(max_s) + sum(exp(s))).
// Q pre-scaled by log2e; each score's exp is ONE v_exp_f32.
// grid 512 blocks (32 bh x 16 qt), 512 threads (8 waves): 4 q-subtiles x 2 k-halves.
// Block decode g=bx>>5: blocks 0-255 heavy (qt=15-g), 256-511 light (qt=g-8).
// With XCD round-robin (bx%8) this gives EVERY CU one heavy + one light block
// whose qt's sum to exactly 15 -> 17 work-units per CU, perfectly balanced.
// (Round-7 experiment: pairing qt by bx&1 broke XCD parity balance, -5us. Do
// NOT key work size to low bits of blockIdx.)
// LDS 72KB: Kdbuf 2x16KB (0..32767) | Vdbuf 2x16KB (32768..65535) | Ps 8KB.
// ONE barrier per k-tile: prefetches for tile i+1 issued right after the
// barrier drain a full iteration later.
__global__ __launch_bounds__(512, 4) void attn_mfma_kernel(
        const __hip_bfloat16* __restrict__ qkv, const __hip_bfloat16* __restrict__ vt,
        __hip_bfloat16* __restrict__ ctxout) {
    __shared__ __align__(16) unsigned short SMEM[36864];   // 72 KB

    const int bx = blockIdx.x;
    const int g = bx >> 5;
    const int qt = (g < 8) ? 15 - g : g - 8;   // pair heavy+light across grid halves
    const int bh = bx & 31;
    const int t = threadIdx.x;                 // 0..511
    const int lane = t & 63;
    const int w = t >> 6;                      // 0..7
    const int half = w >> 2;                   // k-half
    const int wq = w & 3;                      // q-subtile
    const int r16 = lane & 15;
    const int quad = lane >> 4;
    const int qbase = qt * 128 + wq * 32;
    const int swz = quad ^ ((r16 >> 1) & 3);   // K/V read chunk swizzle
    const int pkey = (r16 >> 1) & 3;           // Ps chunk swizzle key

    const __hip_bfloat16* Qg = qkv + (size_t)bh * BH_ELEMS;
    const __hip_bfloat16* Kg = qkv + (size_t)QKV_STRIDE + (size_t)bh * BH_ELEMS;
    const __hip_bfloat16* Vtg = vt + (size_t)bh * BH_ELEMS;   // [d][seq]

    unsigned short* PsW = SMEM + 32768 + w * 512;  // 1KB/wave: [16 q][32 k] swizzled

    // staging chunk decomposition (chunk id cb = t&511 of a 512-chunk tile-pair)
    const int cb_kp = (t & 511) >> 8;
    const int cb_rr = ((t & 511) >> 2) & 63;
    const int cb_cg = ((t & 511) & 3) ^ ((cb_rr >> 1) & 3);

    bf16x8 bq[2][2];
#pragma unroll
    for (int ng = 0; ng < 2; ng++)
#pragma unroll
        for (int kp = 0; kp < 2; kp++)
            bq[ng][kp] = *(const bf16x8*)(Qg + (size_t)(qbase + ng * 16 + r16) * 64 +
                                          kp * 32 + quad * 8);

    f32x4 oT[4][2];
#pragma unroll
    for (int mt = 0; mt < 4; mt++)
#pragma unroll
        for (int ng = 0; ng < 2; ng++) oT[mt][ng] = (f32x4){0.f, 0.f, 0.f, 0.f};
    float m_run[2] = {-1e30f, -1e30f};
    float z_run[2] = {0.f, 0.f};

    const int niter = qt + 1;

    // prologue: stage K(0) and V(0) (tiles 0 and qt+1) into buffer 0 of each dbuf
#pragma unroll
    for (int it = 0; it < 2; it++) {
        int cl = it * 512 + t;
        int ktile = (cl >> 9) ? (qt + 1) : 0;
        async_copy16(Kg + (size_t)(ktile * 64 + cb_rr) * 64 + cb_kp * 32 + cb_cg * 8,
                     (char*)SMEM + (size_t)cl * 16);
        async_copy16(Vtg + (size_t)cb_rr * SEQ + ktile * 64 + cb_kp * 32 + cb_cg * 8,
                     (char*)SMEM + 32768 + (size_t)cl * 16);
    }

#pragma unroll 1
    for (int i = 0; i < niter; i++) {
        const int curb = i & 1;
        __syncthreads();   // K(i),V(i) landed; all waves done with K(i-1),V(i-1)

        // prefetch K(i+1),V(i+1) into the other buffers (consumed next iter)
        if (i + 1 < niter) {
            int ktA = i + 1;
            int ktB = qt + 2 + i; if (ktB > 31) ktB = 31;   // defensive clamp
#pragma unroll
            for (int it = 0; it < 2; it++) {
                int cl = it * 512 + t;
                int ktile = (cl >> 9) ? ktB : ktA;
                async_copy16(Kg + (size_t)(ktile * 64 + cb_rr) * 64 + cb_kp * 32 + cb_cg * 8,
                             (char*)SMEM + (size_t)(curb ^ 1) * 16384 + (size_t)cl * 16);
                async_copy16(Vtg + (size_t)cb_rr * SEQ + ktile * 64 + cb_kp * 32 + cb_cg * 8,
                             (char*)SMEM + 32768 + (size_t)(curb ^ 1) * 16384 + (size_t)cl * 16);
            }
        }

        const int ktile = half ? (qt + 1 + i) : i;
        const bool active = (ktile * 64 <= qbase + 31);

        if (active) {
            const unsigned short* KsW = SMEM + curb * 8192 + half * 4096;  // ushort offs
            f32x4 st[4][2];
#pragma unroll
            for (int mt = 0; mt < 4; mt++)
#pragma unroll
                for (int ng = 0; ng < 2; ng++) st[mt][ng] = (f32x4){0.f, 0.f, 0.f, 0.f};
#pragma unroll
            for (int mt = 0; mt < 4; mt++)
#pragma unroll
                for (int kp = 0; kp < 2; kp++) {
                    bf16x8 ak = *(const bf16x8*)&KsW[kp * 2048 + (mt * 16 + r16) * 32 + swz * 8];
                    st[mt][0] = __builtin_amdgcn_mfma_f32_16x16x32_bf16(ak, bq[0][kp], st[mt][0], 0, 0, 0);
                    st[mt][1] = __builtin_amdgcn_mfma_f32_16x16x32_bf16(ak, bq[1][kp], st[mt][1], 0, 0, 0);
                }

            // causal mask (diagonal-straddling tiles only; wave-uniform branch)
            if (ktile * 64 + 63 > qbase) {
#pragma unroll
                for (int mt = 0; mt < 4; mt++) {
                    int kb = ktile * 64 + mt * 16 + quad * 4;
#pragma unroll
                    for (int ng = 0; ng < 2; ng++) {
                        int q = qbase + ng * 16 + r16;
#pragma unroll
                        for (int r = 0; r < 4; r++)
                            if (kb + r > q) st[mt][ng][r] = -__builtin_inff();
                    }
                }
            }

            // unshifted exp2 via raw v_exp_f32; st becomes P; m,z per lane
#pragma unroll
            for (int mt = 0; mt < 4; mt++)
#pragma unroll
                for (int ng = 0; ng < 2; ng++) {
                    float s0 = st[mt][ng][0], s1 = st[mt][ng][1];
                    float s2 = st[mt][ng][2], s3 = st[mt][ng][3];
                    m_run[ng] = fmaxf(m_run[ng], fmaxf(fmaxf(s0, s1), fmaxf(s2, s3)));
                    float p0 = fast_exp2(s0), p1 = fast_exp2(s1);
                    float p2 = fast_exp2(s2), p3 = fast_exp2(s3);
                    z_run[ng] += (p0 + p1) + (p2 + p3);
                    st[mt][ng][0] = p0; st[mt][ng][1] = p1;
                    st[mt][ng][2] = p2; st[mt][ng][3] = p3;
                }

            const unsigned short* VsW = SMEM + 16384 + curb * 8192 + half * 4096;
            // 4 phases: (k-half p) x (q-group ng): pack P into 1KB Ps, then PV.
#pragma unroll
            for (int p = 0; p < 2; p++) {
#pragma unroll
                for (int ng = 0; ng < 2; ng++) {
#pragma unroll
                    for (int ml = 0; ml < 2; ml++) {
                        int mt = p * 2 + ml;
                        ushort4 pk;
                        pk.x = bf16_bits(st[mt][ng][0]);
                        pk.y = bf16_bits(st[mt][ng][1]);
                        pk.z = bf16_bits(st[mt][ng][2]);
                        pk.w = bf16_bits(st[mt][ng][3]);
                        int c = (ml * 2 + (quad >> 1)) ^ pkey;
                        *(ushort4*)&PsW[r16 * 32 + c * 8 + (quad & 1) * 4] = pk;
                    }
                    bf16x8 bp = *(const bf16x8*)&PsW[r16 * 32 + (quad ^ pkey) * 8];
#pragma unroll
                    for (int mt = 0; mt < 4; mt++) {
                        bf16x8 av = *(const bf16x8*)&VsW[p * 2048 + (mt * 16 + r16) * 32 + swz * 8];
                        oT[mt][ng] = __builtin_amdgcn_mfma_f32_16x16x32_bf16(
                            av, bp, oT[mt][ng], 0, 0, 0);
                    }
                }
            }
        }
    }

    // fold per-lane m,z across quads
#pragma unroll
    for (int off = 16; off < 64; off <<= 1)
#pragma unroll
        for (int ng = 0; ng < 2; ng++) {
            m_run[ng] = fmaxf(m_run[ng], __shfl_xor(m_run[ng], off, 64));
            z_run[ng] += __shfl_xor(z_run[ng], off, 64);
        }

    // ---- combine k-halves through LDS (K/V and Ps regions dead) ----
    __syncthreads();
    f32x4* CbO = (f32x4*)SMEM;                        // 32KB
    f32x4* Ml = (f32x4*)((char*)SMEM + 32768);        // 4KB
    if (w >= 4) {
        int w4 = w - 4;
#pragma unroll
        for (int mt = 0; mt < 4; mt++)
#pragma unroll
            for (int ng = 0; ng < 2; ng++)
                CbO[((w4 * 8 + mt * 2 + ng) << 6) + lane] = oT[mt][ng];
        f32x4 ml;
        ml[0] = m_run[0]; ml[1] = m_run[1]; ml[2] = z_run[0]; ml[3] = z_run[1];
        Ml[(w4 << 6) + lane] = ml;
    }
    __syncthreads();
    if (w < 4) {
        f32x4 ml = Ml[(w << 6) + lane];
        float rd[2];
#pragma unroll
        for (int ng = 0; ng < 2; ng++) {
            float mtot = fmaxf(m_run[ng], ml[ng]);
            float ztot = z_run[ng] + ml[2 + ng];
            rd[ng] = 1.f / (fast_exp2(mtot) + ztot);  // quiet softmax denominator
        }
        const int b = bh >> 4, h = bh & 15;
#pragma unroll
        for (int mt = 0; mt < 4; mt++)
#pragma unroll
            for (int ng = 0; ng < 2; ng++) {
                f32x4 O1 = CbO[((w * 8 + mt * 2 + ng) << 6) + lane];
                int q = qbase + ng * 16 + r16;
                ushort4 pk;
                pk.x = bf16_bits((oT[mt][ng][0] + O1[0]) * rd[ng]);
                pk.y = bf16_bits((oT[mt][ng][1] + O1[1]) * rd[ng]);
                pk.z = bf16_bits((oT[mt][ng][2] + O1[2]) * rd[ng]);
                pk.w = bf16_bits((oT[mt][ng][3] + O1[3]) * rd[ng]);
                *(ushort4*)(ctxout + ((size_t)(b * SEQ + q)) * DIMN + h * 64 +
                            mt * 16 + quad * 4) = pk;
            }
    }
}

// ---------------- launch ----------------

extern "C" void kernel_launch(void* const* d_in, const int* in_sizes, int n_in,
                              void* d_out, int out_size, void* d_ws, size_t ws_size,
                              hipStream_t stream) {
    const float* x  = (const float*)d_in[0];
    const float* Wq = (const float*)d_in[1];
    const float* bq = (const float*)d_in[2];
    const float* Wk = (const float*)d_in[3];
    const float* bk = (const float*)d_in[4];
    const float* Wv = (const float*)d_in[5];
    const float* bv = (const float*)d_in[6];
    const float* Wo = (const float*)d_in[7];
    const float* bo = (const float*)d_in[8];

    char* ws = (char*)d_ws;
    __hip_bfloat16* xbf   = (__hip_bfloat16*)(ws);                           // 8 MB
    __hip_bfloat16* wqkvt = (__hip_bfloat16*)(ws + (8u << 20));              // 6 MB
    __hip_bfloat16* wot   = (__hip_bfloat16*)(ws + (14u << 20));             // 2 MB
    float*          biasq = (float*)(ws + (16u << 20));                      // 12 KB (pad 64K)
    __hip_bfloat16* qkv   = (__hip_bfloat16*)(ws + (16u << 20) + 65536u);    // 16 MB (Q,K)
    __hip_bfloat16* vt    = (__hip_bfloat16*)(ws + (16u << 20) + 65536u + (16u << 20)); // 8 MB
    __hip_bfloat16* ctx   = (__hip_bfloat16*)(ws + (16u << 20) + 65536u + (24u << 20)); // 8 MB
    float* out = (float*)d_out;

    prep_kernel<<<8195, 256, 0, stream>>>(x, bq, bk, bv, Wq, Wk, Wv, Wo,
                                          xbf, biasq, wqkvt, wot);
    gemm_qkv_kernel<<<dim3(16, 16), 512, 0, stream>>>(xbf, wqkvt, biasq, qkv, vt);
    attn_mfma_kernel<<<512, 512, 0, stream>>>(qkv, vt, ctx);
    gemm_out_kernel<<<dim3(8, 64), 256, 0, stream>>>(ctx, wot, bo, out);
}

// Round 11
// 170.273 us; speedup vs baseline: 1.0915x; 1.0123x over previous
//
#include <hip/hip_runtime.h>
#include <hip/hip_bf16.h>
#include <cstdint>
#include <cstddef>

// Problem constants
#define DIMN 1024
#define NHEAD 16
#define HDIM 64
#define NB 2
#define SEQ 2048
#define MROWS 4096           // NB*SEQ
#define BHN 32               // NB*NHEAD
#define QKV_STRIDE 4194304   // BHN*SEQ*HDIM (Q,K regions)
#define BH_ELEMS 131072      // SEQ*HDIM = 64*2048

// Q pre-scale: 1/sqrt(64) * log2(e), so attn uses a single v_exp_f32 per score.
#define QSCALE 0.18033688011112042f

typedef float f32x4 __attribute__((ext_vector_type(4)));
typedef __bf16 bf16x8 __attribute__((ext_vector_type(8)));

__device__ __forceinline__ void async_copy16(const void* g, void* l) {
    __builtin_amdgcn_global_load_lds(
        (__attribute__((address_space(1))) void*)(g),
        (__attribute__((address_space(3))) void*)(l), 16, 0, 0);
}

__device__ __forceinline__ unsigned short bf16_bits(float f) {
    __hip_bfloat16 hb = __float2bfloat16(f);
    return *(unsigned short*)&hb;
}

// raw v_exp_f32 (2^x). OCML exp2f adds subnormal fixup code (~4 VALU); the
// raw instruction is 1 op and handles -inf -> 0 correctly.
__device__ __forceinline__ float fast_exp2(float x) {
    return __builtin_amdgcn_exp2f(x);
}

// ---------------- fused prep: x->bf16, bias concat, W transposes ----------------
__global__ __launch_bounds__(256) void prep_kernel(
        const float* __restrict__ x, const float* __restrict__ bq,
        const float* __restrict__ bk, const float* __restrict__ bv,
        const float* __restrict__ Wq, const float* __restrict__ Wk,
        const float* __restrict__ Wv, const float* __restrict__ Wo,
        __hip_bfloat16* __restrict__ xbf, float* __restrict__ biasq,
        __hip_bfloat16* __restrict__ wqkvt, __hip_bfloat16* __restrict__ wot) {
    __shared__ float tile[32][33];
    const int bid = blockIdx.x;
    const int t = threadIdx.x;
    if (bid < 4096) {
        int i = (bid * 256 + t) * 4;
        float4 v = *(const float4*)(x + i);
        xbf[i + 0] = __float2bfloat16(v.x);
        xbf[i + 1] = __float2bfloat16(v.y);
        xbf[i + 2] = __float2bfloat16(v.z);
        xbf[i + 3] = __float2bfloat16(v.w);
    } else if (bid < 4099) {
        int base = (bid - 4096) * 1024 + t * 4;
#pragma unroll
        for (int e = 0; e < 4; e++) {
            int gi = base + e;
            int which = gi >> 10, off = gi & 1023;
            float v = (which == 0) ? bq[off] : (which == 1) ? bk[off] : bv[off];
            biasq[gi] = v;
        }
    } else {
        int rr = bid - 4099;
        int z = rr >> 10;                      // 0..3 -> Wq,Wk,Wv,Wo
        int tid = rr & 1023;
        int n0 = (tid & 31) * 32, k0 = (tid >> 5) * 32;
        const float* in = (z == 0) ? Wq : (z == 1) ? Wk : (z == 2) ? Wv : Wo;
        __hip_bfloat16* out = (z == 3) ? wot : wqkvt + (size_t)z * DIMN * DIMN;
        int tx = t & 31, ty = t >> 5;          // 32 x 8
#pragma unroll
        for (int r = 0; r < 32; r += 8)
            tile[ty + r][tx] = in[(size_t)(k0 + ty + r) * DIMN + n0 + tx];
        __syncthreads();
#pragma unroll
        for (int r = 0; r < 32; r += 8)
            out[(size_t)(n0 + ty + r) * DIMN + k0 + tx] =
                __float2bfloat16(tile[tx][ty + r]);
    }
}

// ---------------- QKV GEMM: 256x192 tile, ring-3, ONE barrier / K-tile ----------------
// (unchanged from round 10 — measured win; all 256 CUs host one block)
__global__ __launch_bounds__(512, 1) void gemm_qkv_kernel(
        const __hip_bfloat16* __restrict__ A, const __hip_bfloat16* __restrict__ Bt,
        const float* __restrict__ bias, __hip_bfloat16* __restrict__ qkv,
        __hip_bfloat16* __restrict__ vt) {
    __shared__ __align__(16) unsigned short SM[43008];   // 84 KB: A 48KB | B 36KB
    const int t = threadIdx.x;                 // 0..511
    const int m0 = blockIdx.y * 256;
    const int n0 = blockIdx.x * 192;
    const int lane = t & 63;
    const int w = t >> 6;
    const int wmid = w >> 2;                   // 0..1 (M)
    const int wnid = w & 3;                    // 0..3 (N)
    const int r16 = lane & 15;
    const int quad = lane >> 4;
    const int rsw = (quad ^ ((r16 >> 1) & 3)) * 8;   // swizzled read chunk (ushorts)
    const bool bstage2 = (w < 4);              // wave-uniform B second-instruction

    const int srow = t >> 2;                   // 0..127
    const int scsw = (t & 3) ^ ((srow >> 1) & 3);
    const __hip_bfloat16* Ag  = A  + (size_t)(m0 + srow) * DIMN + scsw * 8;
    const __hip_bfloat16* Bg1 = Bt + (size_t)(n0 + srow) * DIMN + scsw * 8;
    const __hip_bfloat16* Bg2 = Bt + (size_t)(n0 + 128 + srow) * DIMN + scsw * 8;

    f32x4 acc[8][3];
#pragma unroll
    for (int i = 0; i < 8; i++)
#pragma unroll
        for (int j = 0; j < 3; j++) acc[i][j] = (f32x4){0.f, 0.f, 0.f, 0.f};

    // prologue: stage tiles 0 (slot 0) and 1 (slot 1)
#pragma unroll
    for (int tt = 0; tt < 2; tt++) {
#pragma unroll
        for (int h = 0; h < 2; h++)
            async_copy16(Ag + (size_t)h * 131072 + tt * 32,
                         (char*)(SM + (tt * 2 + h) * 4096 + t * 8));
        async_copy16(Bg1 + tt * 32, (char*)(SM + 24576 + tt * 6144 + t * 8));
        if (bstage2)
            async_copy16(Bg2 + tt * 32,
                         (char*)(SM + 24576 + tt * 6144 + 4096 + t * 8));
    }

    int sl = 0;                                // tile % 3
#pragma unroll 1
    for (int tt = 0; tt < 32; ++tt) {
        const int sl2 = (sl >= 1) ? (sl - 1) : 2;   // (tt+2) % 3
        // tile-top wait: tile tt landed; allow tile tt+1's batch in flight
        if (tt == 31) {
            asm volatile("s_waitcnt vmcnt(0)" ::: "memory");
        } else if (bstage2) {
            asm volatile("s_waitcnt vmcnt(4)" ::: "memory");
        } else {
            asm volatile("s_waitcnt vmcnt(3)" ::: "memory");
        }
        __builtin_amdgcn_s_barrier();

        const unsigned short* Asl = SM + (sl * 2 + wmid) * 4096;
        const unsigned short* Bsl = SM + 24576 + sl * 6144;

        // all fragment reads for the tile (11 x ds_read_b128)
        bf16x8 af[8], bfr[3];
#pragma unroll
        for (int i = 0; i < 8; i++)
            af[i] = *(const bf16x8*)&Asl[(i * 16 + r16) * 32 + rsw];
#pragma unroll
        for (int j = 0; j < 3; j++)
            bfr[j] = *(const bf16x8*)&Bsl[(wnid * 48 + j * 16 + r16) * 32 + rsw];

        // stage tile tt+2 into slot sl2
        if (tt < 30) {
#pragma unroll
            for (int h = 0; h < 2; h++)
                async_copy16(Ag + (size_t)h * 131072 + (tt + 2) * 32,
                             (char*)(SM + (sl2 * 2 + h) * 4096 + t * 8));
            async_copy16(Bg1 + (tt + 2) * 32,
                         (char*)(SM + 24576 + sl2 * 6144 + t * 8));
            if (bstage2)
                async_copy16(Bg2 + (tt + 2) * 32,
                             (char*)(SM + 24576 + sl2 * 6144 + 4096 + t * 8));
        }

        // 24 MFMA, one cluster per barrier
        __builtin_amdgcn_s_setprio(1);
#pragma unroll
        for (int i = 0; i < 8; i++)
#pragma unroll
            for (int j = 0; j < 3; j++)
                acc[i][j] = __builtin_amdgcn_mfma_f32_16x16x32_bf16(
                    af[i], bfr[j], acc[i][j], 0, 0, 0);
        __builtin_amdgcn_s_setprio(0);

        sl = (sl < 2) ? (sl + 1) : 0;
    }

    // ---- epilogue ('which' is per-fragment uniform: nb is 16-aligned and
    // region boundaries are multiples of 1024)
#pragma unroll
    for (int j = 0; j < 3; j++) {
        const int nb = n0 + wnid * 48 + j * 16;
        const int n = nb + r16;
        const float bv = bias[n];
        const int which = nb >> 10;
        const int rem = n & 1023;
        const int hh = rem >> 6, d = rem & 63;
#pragma unroll
        for (int i = 0; i < 8; i++) {
            const int mbase = m0 + wmid * 128 + i * 16 + quad * 4;
            const int b = mbase >> 11;
            const int lrow = mbase & 2047;
            const int bh = b * NHEAD + hh;
            if (which == 2) {
                ushort4 pk;
                pk.x = bf16_bits(acc[i][j][0] + bv);
                pk.y = bf16_bits(acc[i][j][1] + bv);
                pk.z = bf16_bits(acc[i][j][2] + bv);
                pk.w = bf16_bits(acc[i][j][3] + bv);
                *(ushort4*)(vt + (size_t)bh * BH_ELEMS + (size_t)d * SEQ + lrow) = pk;
            } else {
#pragma unroll
                for (int r = 0; r < 4; r++) {
                    float v = acc[i][j][r] + bv;
                    if (which == 0) v *= QSCALE;   // fold 1/sqrt(hd)*log2e into Q
                    qkv[(size_t)which * QKV_STRIDE + (size_t)bh * BH_ELEMS +
                        (size_t)(lrow + r) * 64 + d] = __float2bfloat16(v);
                }
            }
        }
    }
}

// ---------------- output GEMM: 64x128 tiles, ring-3, ONE barrier / K-tile ----------------
// Transplant of the qkv schedule (verified twice, bit-identical math) onto the
// 2-sync gemm_out: ring-3 K-tile LDS (3 x (A 4KB + B 8KB) = 36 KB -> still
// 2 blocks/CU at 72 KB), counted vmcnt(3) at tile-top (3 loads/thread/tile;
// never 0 until the last tile), ONE raw s_barrier per tile, XOR-swizzled
// staging + reads (kills the 8-way ds_read_b128 conflict of the linear BK=32
// layout), setprio around the 8-MFMA cluster. Per-acc K order unchanged ->
// output bit-identical to the 2-sync version.
__global__ __launch_bounds__(256) void gemm_out_kernel(
        const __hip_bfloat16* __restrict__ A, const __hip_bfloat16* __restrict__ Bt,
        const float* __restrict__ bias, float* __restrict__ outp) {
    __shared__ __align__(16) unsigned short SM[18432];   // 36 KB: A 12KB | B 24KB
    const int t = threadIdx.x;                 // 0..255
    const int m0 = blockIdx.y * 64;
    const int n0 = blockIdx.x * 128;
    const int lane = t & 63;
    const int w = t >> 6;
    const int wm = (w >> 1) * 32;
    const int wn = (w & 1) * 64;
    const int r16 = lane & 15;
    const int quad = lane >> 4;
    const int rsw = (quad ^ ((r16 >> 1) & 3)) * 8;   // swizzled read chunk (ushorts)

    const int srow = t >> 2;                   // 0..63
    const int sc = t & 3;
    const int scswA = sc ^ ((srow >> 1) & 3);
    // B rows: issue0 = srow, issue1 = srow+64; (row>>1)&3 identical for both
    const __hip_bfloat16* Ag  = A  + (size_t)(m0 + srow) * DIMN + scswA * 8;
    const __hip_bfloat16* Bg1 = Bt + (size_t)(n0 + srow) * DIMN + scswA * 8;
    const __hip_bfloat16* Bg2 = Bt + (size_t)(n0 + 64 + srow) * DIMN + scswA * 8;

    f32x4 acc[2][4];
#pragma unroll
    for (int i = 0; i < 2; i++)
#pragma unroll
        for (int j = 0; j < 4; j++) acc[i][j] = (f32x4){0.f, 0.f, 0.f, 0.f};

    // prologue: stage tiles 0 (slot 0) and 1 (slot 1): A + B1 + B2 each
#pragma unroll
    for (int tt = 0; tt < 2; tt++) {
        async_copy16(Ag + tt * 32, (char*)(SM + tt * 2048 + t * 8));
        async_copy16(Bg1 + tt * 32, (char*)(SM + 6144 + tt * 4096 + t * 8));
        async_copy16(Bg2 + tt * 32, (char*)(SM + 6144 + tt * 4096 + 2048 + t * 8));
    }

    int sl = 0;                                // tile % 3
#pragma unroll 1
    for (int tt = 0; tt < 32; ++tt) {
        const int sl2 = (sl >= 1) ? (sl - 1) : 2;   // (tt+2) % 3
        if (tt == 31) {
            asm volatile("s_waitcnt vmcnt(0)" ::: "memory");
        } else {
            asm volatile("s_waitcnt vmcnt(3)" ::: "memory");
        }
        __builtin_amdgcn_s_barrier();

        const unsigned short* Asl = SM + sl * 2048;
        const unsigned short* Bsl = SM + 6144 + sl * 4096;

        // fragment reads (6 x ds_read_b128, conflict-free via rsw)
        bf16x8 af[2], bfr[4];
#pragma unroll
        for (int i = 0; i < 2; i++)
            af[i] = *(const bf16x8*)&Asl[(wm + i * 16 + r16) * 32 + rsw];
#pragma unroll
        for (int j = 0; j < 4; j++)
            bfr[j] = *(const bf16x8*)&Bsl[(wn + j * 16 + r16) * 32 + rsw];

        // stage tile tt+2 into slot sl2 (3 loads/thread; fly for 2 tiles)
        if (tt < 30) {
            async_copy16(Ag + (tt + 2) * 32, (char*)(SM + sl2 * 2048 + t * 8));
            async_copy16(Bg1 + (tt + 2) * 32,
                         (char*)(SM + 6144 + sl2 * 4096 + t * 8));
            async_copy16(Bg2 + (tt + 2) * 32,
                         (char*)(SM + 6144 + sl2 * 4096 + 2048 + t * 8));
        }

        // 8 MFMA, one cluster per barrier
        __builtin_amdgcn_s_setprio(1);
#pragma unroll
        for (int i = 0; i < 2; i++)
#pragma unroll
            for (int j = 0; j < 4; j++)
                acc[i][j] = __builtin_amdgcn_mfma_f32_16x16x32_bf16(
                    af[i], bfr[j], acc[i][j], 0, 0, 0);
        __builtin_amdgcn_s_setprio(0);

        sl = (sl < 2) ? (sl + 1) : 0;
    }

#pragma unroll
    for (int i = 0; i < 2; i++)
#pragma unroll
        for (int j = 0; j < 4; j++) {
            int n = n0 + wn + j * 16 + r16;
            float bv = bias[n];
#pragma unroll
            for (int r = 0; r < 4; r++) {
                int m = m0 + wm + i * 16 + quad * 4 + r;
                outp[(size_t)m * DIMN + n] = acc[i][j][r] + bv;
            }
        }
}

// ---------------- MFMA flash attention, single-barrier deep pipeline ----------------
// (unchanged from round 10 — balanced decode, fast_exp2, 72 KB, one barrier/tile)
__global__ __launch_bounds__(512, 4) void attn_mfma_kernel(
        const __hip_bfloat16* __restrict__ qkv, const __hip_bfloat16* __restrict__ vt,
        __hip_bfloat16* __restrict__ ctxout) {
    __shared__ __align__(16) unsigned short SMEM[36864];   // 72 KB

    const int bx = blockIdx.x;
    const int g = bx >> 5;
    const int qt = (g < 8) ? 15 - g : g - 8;   // pair heavy+light across grid halves
    const int bh = bx & 31;
    const int t = threadIdx.x;                 // 0..511
    const int lane = t & 63;
    const int w = t >> 6;                      // 0..7
    const int half = w >> 2;                   // k-half
    const int wq = w & 3;                      // q-subtile
    const int r16 = lane & 15;
    const int quad = lane >> 4;
    const int qbase = qt * 128 + wq * 32;
    const int swz = quad ^ ((r16 >> 1) & 3);   // K/V read chunk swizzle
    const int pkey = (r16 >> 1) & 3;           // Ps chunk swizzle key

    const __hip_bfloat16* Qg = qkv + (size_t)bh * BH_ELEMS;
    const __hip_bfloat16* Kg = qkv + (size_t)QKV_STRIDE + (size_t)bh * BH_ELEMS;
    const __hip_bfloat16* Vtg = vt + (size_t)bh * BH_ELEMS;   // [d][seq]

    unsigned short* PsW = SMEM + 32768 + w * 512;  // 1KB/wave: [16 q][32 k] swizzled

    // staging chunk decomposition (chunk id cb = t&511 of a 512-chunk tile-pair)
    const int cb_kp = (t & 511) >> 8;
    const int cb_rr = ((t & 511) >> 2) & 63;
    const int cb_cg = ((t & 511) & 3) ^ ((cb_rr >> 1) & 3);

    bf16x8 bq[2][2];
#pragma unroll
    for (int ng = 0; ng < 2; ng++)
#pragma unroll
        for (int kp = 0; kp < 2; kp++)
            bq[ng][kp] = *(const bf16x8*)(Qg + (size_t)(qbase + ng * 16 + r16) * 64 +
                                          kp * 32 + quad * 8);

    f32x4 oT[4][2];
#pragma unroll
    for (int mt = 0; mt < 4; mt++)
#pragma unroll
        for (int ng = 0; ng < 2; ng++) oT[mt][ng] = (f32x4){0.f, 0.f, 0.f, 0.f};
    float m_run[2] = {-1e30f, -1e30f};
    float z_run[2] = {0.f, 0.f};

    const int niter = qt + 1;

    // prologue: stage K(0) and V(0) (tiles 0 and qt+1) into buffer 0 of each dbuf
#pragma unroll
    for (int it = 0; it < 2; it++) {
        int cl = it * 512 + t;
        int ktile = (cl >> 9) ? (qt + 1) : 0;
        async_copy16(Kg + (size_t)(ktile * 64 + cb_rr) * 64 + cb_kp * 32 + cb_cg * 8,
                     (char*)SMEM + (size_t)cl * 16);
        async_copy16(Vtg + (size_t)cb_rr * SEQ + ktile * 64 + cb_kp * 32 + cb_cg * 8,
                     (char*)SMEM + 32768 + (size_t)cl * 16);
    }

#pragma unroll 1
    for (int i = 0; i < niter; i++) {
        const int curb = i & 1;
        __syncthreads();   // K(i),V(i) landed; all waves done with K(i-1),V(i-1)

        // prefetch K(i+1),V(i+1) into the other buffers (consumed next iter)
        if (i + 1 < niter) {
            int ktA = i + 1;
            int ktB = qt + 2 + i; if (ktB > 31) ktB = 31;   // defensive clamp
#pragma unroll
            for (int it = 0; it < 2; it++) {
                int cl = it * 512 + t;
                int ktile = (cl >> 9) ? ktB : ktA;
                async_copy16(Kg + (size_t)(ktile * 64 + cb_rr) * 64 + cb_kp * 32 + cb_cg * 8,
                             (char*)SMEM + (size_t)(curb ^ 1) * 16384 + (size_t)cl * 16);
                async_copy16(Vtg + (size_t)cb_rr * SEQ + ktile * 64 + cb_kp * 32 + cb_cg * 8,
                             (char*)SMEM + 32768 + (size_t)(curb ^ 1) * 16384 + (size_t)cl * 16);
            }
        }

        const int ktile = half ? (qt + 1 + i) : i;
        const bool active = (ktile * 64 <= qbase + 31);

        if (active) {
            const unsigned short* KsW = SMEM + curb * 8192 + half * 4096;  // ushort offs
            f32x4 st[4][2];
#pragma unroll
            for (int mt = 0; mt < 4; mt++)
#pragma unroll
                for (int ng = 0; ng < 2; ng++) st[mt][ng] = (f32x4){0.f, 0.f, 0.f, 0.f};
#pragma unroll
            for (int mt = 0; mt < 4; mt++)
#pragma unroll
                for (int kp = 0; kp < 2; kp++) {
                    bf16x8 ak = *(const bf16x8*)&KsW[kp * 2048 + (mt * 16 + r16) * 32 + swz * 8];
                    st[mt][0] = __builtin_amdgcn_mfma_f32_16x16x32_bf16(ak, bq[0][kp], st[mt][0], 0, 0, 0);
                    st[mt][1] = __builtin_amdgcn_mfma_f32_16x16x32_bf16(ak, bq[1][kp], st[mt][1], 0, 0, 0);
                }

            // causal mask (diagonal-straddling tiles only; wave-uniform branch)
            if (ktile * 64 + 63 > qbase) {
#pragma unroll
                for (int mt = 0; mt < 4; mt++) {
                    int kb = ktile * 64 + mt * 16 + quad * 4;
#pragma unroll
                    for (int ng = 0; ng < 2; ng++) {
                        int q = qbase + ng * 16 + r16;
#pragma unroll
                        for (int r = 0; r < 4; r++)
                            if (kb + r > q) st[mt][ng][r] = -__builtin_inff();
                    }
                }
            }

            // unshifted exp2 via raw v_exp_f32; st becomes P; m,z per lane
#pragma unroll
            for (int mt = 0; mt < 4; mt++)
#pragma unroll
                for (int ng = 0; ng < 2; ng++) {
                    float s0 = st[mt][ng][0], s1 = st[mt][ng][1];
                    float s2 = st[mt][ng][2], s3 = st[mt][ng][3];
                    m_run[ng] = fmaxf(m_run[ng], fmaxf(fmaxf(s0, s1), fmaxf(s2, s3)));
                    float p0 = fast_exp2(s0), p1 = fast_exp2(s1);
                    float p2 = fast_exp2(s2), p3 = fast_exp2(s3);
                    z_run[ng] += (p0 + p1) + (p2 + p3);
                    st[mt][ng][0] = p0; st[mt][ng][1] = p1;
                    st[mt][ng][2] = p2; st[mt][ng][3] = p3;
                }

            const unsigned short* VsW = SMEM + 16384 + curb * 8192 + half * 4096;
            // 4 phases: (k-half p) x (q-group ng): pack P into 1KB Ps, then PV.
#pragma unroll
            for (int p = 0; p < 2; p++) {
#pragma unroll
                for (int ng = 0; ng < 2; ng++) {
#pragma unroll
                    for (int ml = 0; ml < 2; ml++) {
                        int mt = p * 2 + ml;
                        ushort4 pk;
                        pk.x = bf16_bits(st[mt][ng][0]);
                        pk.y = bf16_bits(st[mt][ng][1]);
                        pk.z = bf16_bits(st[mt][ng][2]);
                        pk.w = bf16_bits(st[mt][ng][3]);
                        int c = (ml * 2 + (quad >> 1)) ^ pkey;
                        *(ushort4*)&PsW[r16 * 32 + c * 8 + (quad & 1) * 4] = pk;
                    }
                    bf16x8 bp = *(const bf16x8*)&PsW[r16 * 32 + (quad ^ pkey) * 8];
#pragma unroll
                    for (int mt = 0; mt < 4; mt++) {
                        bf16x8 av = *(const bf16x8*)&VsW[p * 2048 + (mt * 16 + r16) * 32 + swz * 8];
                        oT[mt][ng] = __builtin_amdgcn_mfma_f32_16x16x32_bf16(
                            av, bp, oT[mt][ng], 0, 0, 0);
                    }
                }
            }
        }
    }

    // fold per-lane m,z across quads
#pragma unroll
    for (int off = 16; off < 64; off <<= 1)
#pragma unroll
        for (int ng = 0; ng < 2; ng++) {
            m_run[ng] = fmaxf(m_run[ng], __shfl_xor(m_run[ng], off, 64));
            z_run[ng] += __shfl_xor(z_run[ng], off, 64);
        }

    // ---- combine k-halves through LDS (K/V and Ps regions dead) ----
    __syncthreads();
    f32x4* CbO = (f32x4*)SMEM;                        // 32KB
    f32x4* Ml = (f32x4*)((char*)SMEM + 32768);        // 4KB
    if (w >= 4) {
        int w4 = w - 4;
#pragma unroll
        for (int mt = 0; mt < 4; mt++)
#pragma unroll
            for (int ng = 0; ng < 2; ng++)
                CbO[((w4 * 8 + mt * 2 + ng) << 6) + lane] = oT[mt][ng];
        f32x4 ml;
        ml[0] = m_run[0]; ml[1] = m_run[1]; ml[2] = z_run[0]; ml[3] = z_run[1];
        Ml[(w4 << 6) + lane] = ml;
    }
    __syncthreads();
    if (w < 4) {
        f32x4 ml = Ml[(w << 6) + lane];
        float rd[2];
#pragma unroll
        for (int ng = 0; ng < 2; ng++) {
            float mtot = fmaxf(m_run[ng], ml[ng]);
            float ztot = z_run[ng] + ml[2 + ng];
            rd[ng] = 1.f / (fast_exp2(mtot) + ztot);  // quiet softmax denominator
        }
        const int b = bh >> 4, h = bh & 15;
#pragma unroll
        for (int mt = 0; mt < 4; mt++)
#pragma unroll
            for (int ng = 0; ng < 2; ng++) {
                f32x4 O1 = CbO[((w * 8 + mt * 2 + ng) << 6) + lane];
                int q = qbase + ng * 16 + r16;
                ushort4 pk;
                pk.x = bf16_bits((oT[mt][ng][0] + O1[0]) * rd[ng]);
                pk.y = bf16_bits((oT[mt][ng][1] + O1[1]) * rd[ng]);
                pk.z = bf16_bits((oT[mt][ng][2] + O1[2]) * rd[ng]);
                pk.w = bf16_bits((oT[mt][ng][3] + O1[3]) * rd[ng]);
                *(ushort4*)(ctxout + ((size_t)(b * SEQ + q)) * DIMN + h * 64 +
                            mt * 16 + quad * 4) = pk;
            }
    }
}

// ---------------- launch ----------------

extern "C" void kernel_launch(void* const* d_in, const int* in_sizes, int n_in,
                              void* d_out, int out_size, void* d_ws, size_t ws_size,
                              hipStream_t stream) {
    const float* x  = (const float*)d_in[0];
    const float* Wq = (const float*)d_in[1];
    const float* bq = (const float*)d_in[2];
    const float* Wk = (const float*)d_in[3];
    const float* bk = (const float*)d_in[4];
    const float* Wv = (const float*)d_in[5];
    const float* bv = (const float*)d_in[6];
    const float* Wo = (const float*)d_in[7];
    const float* bo = (const float*)d_in[8];

    char* ws = (char*)d_ws;
    __hip_bfloat16* xbf   = (__hip_bfloat16*)(ws);                           // 8 MB
    __hip_bfloat16* wqkvt = (__hip_bfloat16*)(ws + (8u << 20));              // 6 MB
    __hip_bfloat16* wot   = (__hip_bfloat16*)(ws + (14u << 20));             // 2 MB
    float*          biasq = (float*)(ws + (16u << 20));                      // 12 KB (pad 64K)
    __hip_bfloat16* qkv   = (__hip_bfloat16*)(ws + (16u << 20) + 65536u);    // 16 MB (Q,K)
    __hip_bfloat16* vt    = (__hip_bfloat16*)(ws + (16u << 20) + 65536u + (16u << 20)); // 8 MB
    __hip_bfloat16* ctx   = (__hip_bfloat16*)(ws + (16u << 20) + 65536u + (24u << 20)); // 8 MB
    float* out = (float*)d_out;

    prep_kernel<<<8195, 256, 0, stream>>>(x, bq, bk, bv, Wq, Wk, Wv, Wo,
                                          xbf, biasq, wqkvt, wot);
    gemm_qkv_kernel<<<dim3(16, 16), 512, 0, stream>>>(xbf, wqkvt, biasq, qkv, vt);
    attn_mfma_kernel<<<512, 512, 0, stream>>>(qkv, vt, ctx);
    gemm_out_kernel<<<dim3(8, 64), 256, 0, stream>>>(ctx, wot, bo, out);
}

// Round 12
// 170.244 us; speedup vs baseline: 1.0917x; 1.0002x over previous
//
#include <hip/hip_runtime.h>
#include <hip/hip_bf16.h>
#include <cstdint>
#include <cstddef>

// Problem constants
#define DIMN 1024
#define NHEAD 16
#define HDIM 64
#define NB 2
#define SEQ 2048
#define MROWS 4096           // NB*SEQ
#define BHN 32               // NB*NHEAD
#define QKV_STRIDE 4194304   // BHN*SEQ*HDIM (Q,K regions)
#define BH_ELEMS 131072      // SEQ*HDIM = 64*2048

// Q pre-scale: 1/sqrt(64) * log2(e), so attn uses a single v_exp_f32 per score.
#define QSCALE 0.18033688011112042f

typedef float f32x4 __attribute__((ext_vector_type(4)));
typedef __bf16 bf16x8 __attribute__((ext_vector_type(8)));

__device__ __forceinline__ void async_copy16(const void* g, void* l) {
    __builtin_amdgcn_global_load_lds(
        (__attribute__((address_space(1))) void*)(g),
        (__attribute__((address_space(3))) void*)(l), 16, 0, 0);
}

__device__ __forceinline__ unsigned short bf16_bits(float f) {
    __hip_bfloat16 hb = __float2bfloat16(f);
    return *(unsigned short*)&hb;
}

// raw v_exp_f32 (2^x). OCML exp2f adds subnormal fixup code (~4 VALU); the
// raw instruction is 1 op and handles -inf -> 0 correctly.
__device__ __forceinline__ float fast_exp2(float x) {
    return __builtin_amdgcn_exp2f(x);
}

// ---------------- fused prep: x->bf16, bias concat, W transposes ----------------
__global__ __launch_bounds__(256) void prep_kernel(
        const float* __restrict__ x, const float* __restrict__ bq,
        const float* __restrict__ bk, const float* __restrict__ bv,
        const float* __restrict__ Wq, const float* __restrict__ Wk,
        const float* __restrict__ Wv, const float* __restrict__ Wo,
        __hip_bfloat16* __restrict__ xbf, float* __restrict__ biasq,
        __hip_bfloat16* __restrict__ wqkvt, __hip_bfloat16* __restrict__ wot) {
    __shared__ float tile[32][33];
    const int bid = blockIdx.x;
    const int t = threadIdx.x;
    if (bid < 4096) {
        int i = (bid * 256 + t) * 4;
        float4 v = *(const float4*)(x + i);
        xbf[i + 0] = __float2bfloat16(v.x);
        xbf[i + 1] = __float2bfloat16(v.y);
        xbf[i + 2] = __float2bfloat16(v.z);
        xbf[i + 3] = __float2bfloat16(v.w);
    } else if (bid < 4099) {
        int base = (bid - 4096) * 1024 + t * 4;
#pragma unroll
        for (int e = 0; e < 4; e++) {
            int gi = base + e;
            int which = gi >> 10, off = gi & 1023;
            float v = (which == 0) ? bq[off] : (which == 1) ? bk[off] : bv[off];
            biasq[gi] = v;
        }
    } else {
        int rr = bid - 4099;
        int z = rr >> 10;                      // 0..3 -> Wq,Wk,Wv,Wo
        int tid = rr & 1023;
        int n0 = (tid & 31) * 32, k0 = (tid >> 5) * 32;
        const float* in = (z == 0) ? Wq : (z == 1) ? Wk : (z == 2) ? Wv : Wo;
        __hip_bfloat16* out = (z == 3) ? wot : wqkvt + (size_t)z * DIMN * DIMN;
        int tx = t & 31, ty = t >> 5;          // 32 x 8
#pragma unroll
        for (int r = 0; r < 32; r += 8)
            tile[ty + r][tx] = in[(size_t)(k0 + ty + r) * DIMN + n0 + tx];
        __syncthreads();
#pragma unroll
        for (int r = 0; r < 32; r += 8)
            out[(size_t)(n0 + ty + r) * DIMN + k0 + tx] =
                __float2bfloat16(tile[tx][ty + r]);
    }
}

// ---------------- QKV GEMM: 256x192 tile, 1024 threads (4 waves/SIMD) ----------------
// grid 16x16 = 256 blocks (1/CU), 1024 threads = 16 waves (4M x 4N), per-wave
// 64x48 output, 12 MFMA/wave/K-tile. Rationale: the 512-thread version ran
// 2 waves/SIMD with MfmaUtil 22 / VALUBusy 13 / Occ 13 — latency-bound with
// both pipes idle; 4 waves/SIMD restores the implicit wave-overlap regime.
// Schedule unchanged (ring-3 slots, counted vmcnt, ONE raw s_barrier/tile,
// XOR swizzle, setprio). LDS 84 KB: A 3x16KB | B 3x12KB.
// Staging per tile: A = 1 load/thread (all 16 waves), B = threads 0..767
// (waves 0..11, wave-uniform) -> per-wave vmcnt/tile = 2 (w<12) or 1 (w>=12).
// Per-acc K accumulation order unchanged -> output bit-identical.
__global__ __launch_bounds__(1024, 4) void gemm_qkv_kernel(
        const __hip_bfloat16* __restrict__ A, const __hip_bfloat16* __restrict__ Bt,
        const float* __restrict__ bias, __hip_bfloat16* __restrict__ qkv,
        __hip_bfloat16* __restrict__ vt) {
    __shared__ __align__(16) unsigned short SM[43008];   // 84 KB: A 48KB | B 36KB
    const int t = threadIdx.x;                 // 0..1023
    const int m0 = blockIdx.y * 256;
    const int n0 = blockIdx.x * 192;
    const int lane = t & 63;
    const int w = t >> 6;                      // 0..15
    const int wmid = w >> 2;                   // 0..3 (M)
    const int wnid = w & 3;                    // 0..3 (N)
    const int r16 = lane & 15;
    const int quad = lane >> 4;
    const int rsw = (quad ^ ((r16 >> 1) & 3)) * 8;   // swizzled read chunk (ushorts)
    const bool bstageB = (w < 12);             // wave-uniform B staging

    const int srow = t >> 2;                   // 0..255 (A); 0..191 used for B
    const int scsw = (t & 3) ^ ((srow >> 1) & 3);
    const __hip_bfloat16* Ag = A  + (size_t)(m0 + srow) * DIMN + scsw * 8;
    const __hip_bfloat16* Bg = Bt + (size_t)(n0 + srow) * DIMN + scsw * 8;  // deref'd only if bstageB

    f32x4 acc[4][3];
#pragma unroll
    for (int i = 0; i < 4; i++)
#pragma unroll
        for (int j = 0; j < 3; j++) acc[i][j] = (f32x4){0.f, 0.f, 0.f, 0.f};

    // prologue: stage tiles 0 (slot 0) and 1 (slot 1)
#pragma unroll
    for (int tt = 0; tt < 2; tt++) {
        async_copy16(Ag + tt * 32, (char*)(SM + tt * 8192 + t * 8));
        if (bstageB)
            async_copy16(Bg + tt * 32, (char*)(SM + 24576 + tt * 6144 + t * 8));
    }

    int sl = 0;                                // tile % 3
#pragma unroll 1
    for (int tt = 0; tt < 32; ++tt) {
        const int sl2 = (sl >= 1) ? (sl - 1) : 2;   // (tt+2) % 3
        // tile-top wait: tile tt landed; allow tile tt+1's batch in flight
        if (tt == 31) {
            asm volatile("s_waitcnt vmcnt(0)" ::: "memory");
        } else if (bstageB) {
            asm volatile("s_waitcnt vmcnt(2)" ::: "memory");
        } else {
            asm volatile("s_waitcnt vmcnt(1)" ::: "memory");
        }
        __builtin_amdgcn_s_barrier();

        const unsigned short* Asl = SM + sl * 8192;
        const unsigned short* Bsl = SM + 24576 + sl * 6144;

        // fragment reads for the tile (7 x ds_read_b128)
        bf16x8 af[4], bfr[3];
#pragma unroll
        for (int i = 0; i < 4; i++)
            af[i] = *(const bf16x8*)&Asl[(wmid * 64 + i * 16 + r16) * 32 + rsw];
#pragma unroll
        for (int j = 0; j < 3; j++)
            bfr[j] = *(const bf16x8*)&Bsl[(wnid * 48 + j * 16 + r16) * 32 + rsw];

        // stage tile tt+2 into slot sl2
        if (tt < 30) {
            async_copy16(Ag + (tt + 2) * 32, (char*)(SM + sl2 * 8192 + t * 8));
            if (bstageB)
                async_copy16(Bg + (tt + 2) * 32,
                             (char*)(SM + 24576 + sl2 * 6144 + t * 8));
        }

        // 12 MFMA, one cluster per barrier
        __builtin_amdgcn_s_setprio(1);
#pragma unroll
        for (int i = 0; i < 4; i++)
#pragma unroll
            for (int j = 0; j < 3; j++)
                acc[i][j] = __builtin_amdgcn_mfma_f32_16x16x32_bf16(
                    af[i], bfr[j], acc[i][j], 0, 0, 0);
        __builtin_amdgcn_s_setprio(0);

        sl = (sl < 2) ? (sl + 1) : 0;
    }

    // ---- epilogue ('which' is per-fragment uniform: nb is 16-aligned and
    // region boundaries are multiples of 1024)
#pragma unroll
    for (int j = 0; j < 3; j++) {
        const int nb = n0 + wnid * 48 + j * 16;
        const int n = nb + r16;
        const float bv = bias[n];
        const int which = nb >> 10;
        const int rem = n & 1023;
        const int hh = rem >> 6, d = rem & 63;
#pragma unroll
        for (int i = 0; i < 4; i++) {
            const int mbase = m0 + wmid * 64 + i * 16 + quad * 4;
            const int b = mbase >> 11;
            const int lrow = mbase & 2047;
            const int bh = b * NHEAD + hh;
            if (which == 2) {
                ushort4 pk;
                pk.x = bf16_bits(acc[i][j][0] + bv);
                pk.y = bf16_bits(acc[i][j][1] + bv);
                pk.z = bf16_bits(acc[i][j][2] + bv);
                pk.w = bf16_bits(acc[i][j][3] + bv);
                *(ushort4*)(vt + (size_t)bh * BH_ELEMS + (size_t)d * SEQ + lrow) = pk;
            } else {
#pragma unroll
                for (int r = 0; r < 4; r++) {
                    float v = acc[i][j][r] + bv;
                    if (which == 0) v *= QSCALE;   // fold 1/sqrt(hd)*log2e into Q
                    qkv[(size_t)which * QKV_STRIDE + (size_t)bh * BH_ELEMS +
                        (size_t)(lrow + r) * 64 + d] = __float2bfloat16(v);
                }
            }
        }
    }
}

// ---------------- output GEMM: 64x128 tiles, ring-3, ONE barrier / K-tile ----------------
// (unchanged from round 11 — measured win)
__global__ __launch_bounds__(256) void gemm_out_kernel(
        const __hip_bfloat16* __restrict__ A, const __hip_bfloat16* __restrict__ Bt,
        const float* __restrict__ bias, float* __restrict__ outp) {
    __shared__ __align__(16) unsigned short SM[18432];   // 36 KB: A 12KB | B 24KB
    const int t = threadIdx.x;                 // 0..255
    const int m0 = blockIdx.y * 64;
    const int n0 = blockIdx.x * 128;
    const int lane = t & 63;
    const int w = t >> 6;
    const int wm = (w >> 1) * 32;
    const int wn = (w & 1) * 64;
    const int r16 = lane & 15;
    const int quad = lane >> 4;
    const int rsw = (quad ^ ((r16 >> 1) & 3)) * 8;   // swizzled read chunk (ushorts)

    const int srow = t >> 2;                   // 0..63
    const int sc = t & 3;
    const int scswA = sc ^ ((srow >> 1) & 3);
    const __hip_bfloat16* Ag  = A  + (size_t)(m0 + srow) * DIMN + scswA * 8;
    const __hip_bfloat16* Bg1 = Bt + (size_t)(n0 + srow) * DIMN + scswA * 8;
    const __hip_bfloat16* Bg2 = Bt + (size_t)(n0 + 64 + srow) * DIMN + scswA * 8;

    f32x4 acc[2][4];
#pragma unroll
    for (int i = 0; i < 2; i++)
#pragma unroll
        for (int j = 0; j < 4; j++) acc[i][j] = (f32x4){0.f, 0.f, 0.f, 0.f};

    // prologue: stage tiles 0 (slot 0) and 1 (slot 1): A + B1 + B2 each
#pragma unroll
    for (int tt = 0; tt < 2; tt++) {
        async_copy16(Ag + tt * 32, (char*)(SM + tt * 2048 + t * 8));
        async_copy16(Bg1 + tt * 32, (char*)(SM + 6144 + tt * 4096 + t * 8));
        async_copy16(Bg2 + tt * 32, (char*)(SM + 6144 + tt * 4096 + 2048 + t * 8));
    }

    int sl = 0;                                // tile % 3
#pragma unroll 1
    for (int tt = 0; tt < 32; ++tt) {
        const int sl2 = (sl >= 1) ? (sl - 1) : 2;   // (tt+2) % 3
        if (tt == 31) {
            asm volatile("s_waitcnt vmcnt(0)" ::: "memory");
        } else {
            asm volatile("s_waitcnt vmcnt(3)" ::: "memory");
        }
        __builtin_amdgcn_s_barrier();

        const unsigned short* Asl = SM + sl * 2048;
        const unsigned short* Bsl = SM + 6144 + sl * 4096;

        // fragment reads (6 x ds_read_b128, conflict-free via rsw)
        bf16x8 af[2], bfr[4];
#pragma unroll
        for (int i = 0; i < 2; i++)
            af[i] = *(const bf16x8*)&Asl[(wm + i * 16 + r16) * 32 + rsw];
#pragma unroll
        for (int j = 0; j < 4; j++)
            bfr[j] = *(const bf16x8*)&Bsl[(wn + j * 16 + r16) * 32 + rsw];

        // stage tile tt+2 into slot sl2 (3 loads/thread; fly for 2 tiles)
        if (tt < 30) {
            async_copy16(Ag + (tt + 2) * 32, (char*)(SM + sl2 * 2048 + t * 8));
            async_copy16(Bg1 + (tt + 2) * 32,
                         (char*)(SM + 6144 + sl2 * 4096 + t * 8));
            async_copy16(Bg2 + (tt + 2) * 32,
                         (char*)(SM + 6144 + sl2 * 4096 + 2048 + t * 8));
        }

        // 8 MFMA, one cluster per barrier
        __builtin_amdgcn_s_setprio(1);
#pragma unroll
        for (int i = 0; i < 2; i++)
#pragma unroll
            for (int j = 0; j < 4; j++)
                acc[i][j] = __builtin_amdgcn_mfma_f32_16x16x32_bf16(
                    af[i], bfr[j], acc[i][j], 0, 0, 0);
        __builtin_amdgcn_s_setprio(0);

        sl = (sl < 2) ? (sl + 1) : 0;
    }

#pragma unroll
    for (int i = 0; i < 2; i++)
#pragma unroll
        for (int j = 0; j < 4; j++) {
            int n = n0 + wn + j * 16 + r16;
            float bv = bias[n];
#pragma unroll
            for (int r = 0; r < 4; r++) {
                int m = m0 + wm + i * 16 + quad * 4 + r;
                outp[(size_t)m * DIMN + n] = acc[i][j][r] + bv;
            }
        }
}

// ---------------- MFMA flash attention, single-barrier deep pipeline ----------------
// (unchanged from round 11 — balanced decode, fast_exp2, 72 KB, one barrier/tile)
__global__ __launch_bounds__(512, 4) void attn_mfma_kernel(
        const __hip_bfloat16* __restrict__ qkv, const __hip_bfloat16* __restrict__ vt,
        __hip_bfloat16* __restrict__ ctxout) {
    __shared__ __align__(16) unsigned short SMEM[36864];   // 72 KB

    const int bx = blockIdx.x;
    const int g = bx >> 5;
    const int qt = (g < 8) ? 15 - g : g - 8;   // pair heavy+light across grid halves
    const int bh = bx & 31;
    const int t = threadIdx.x;                 // 0..511
    const int lane = t & 63;
    const int w = t >> 6;                      // 0..7
    const int half = w >> 2;                   // k-half
    const int wq = w & 3;                      // q-subtile
    const int r16 = lane & 15;
    const int quad = lane >> 4;
    const int qbase = qt * 128 + wq * 32;
    const int swz = quad ^ ((r16 >> 1) & 3);   // K/V read chunk swizzle
    const int pkey = (r16 >> 1) & 3;           // Ps chunk swizzle key

    const __hip_bfloat16* Qg = qkv + (size_t)bh * BH_ELEMS;
    const __hip_bfloat16* Kg = qkv + (size_t)QKV_STRIDE + (size_t)bh * BH_ELEMS;
    const __hip_bfloat16* Vtg = vt + (size_t)bh * BH_ELEMS;   // [d][seq]

    unsigned short* PsW = SMEM + 32768 + w * 512;  // 1KB/wave: [16 q][32 k] swizzled

    // staging chunk decomposition (chunk id cb = t&511 of a 512-chunk tile-pair)
    const int cb_kp = (t & 511) >> 8;
    const int cb_rr = ((t & 511) >> 2) & 63;
    const int cb_cg = ((t & 511) & 3) ^ ((cb_rr >> 1) & 3);

    bf16x8 bq[2][2];
#pragma unroll
    for (int ng = 0; ng < 2; ng++)
#pragma unroll
        for (int kp = 0; kp < 2; kp++)
            bq[ng][kp] = *(const bf16x8*)(Qg + (size_t)(qbase + ng * 16 + r16) * 64 +
                                          kp * 32 + quad * 8);

    f32x4 oT[4][2];
#pragma unroll
    for (int mt = 0; mt < 4; mt++)
#pragma unroll
        for (int ng = 0; ng < 2; ng++) oT[mt][ng] = (f32x4){0.f, 0.f, 0.f, 0.f};
    float m_run[2] = {-1e30f, -1e30f};
    float z_run[2] = {0.f, 0.f};

    const int niter = qt + 1;

    // prologue: stage K(0) and V(0) (tiles 0 and qt+1) into buffer 0 of each dbuf
#pragma unroll
    for (int it = 0; it < 2; it++) {
        int cl = it * 512 + t;
        int ktile = (cl >> 9) ? (qt + 1) : 0;
        async_copy16(Kg + (size_t)(ktile * 64 + cb_rr) * 64 + cb_kp * 32 + cb_cg * 8,
                     (char*)SMEM + (size_t)cl * 16);
        async_copy16(Vtg + (size_t)cb_rr * SEQ + ktile * 64 + cb_kp * 32 + cb_cg * 8,
                     (char*)SMEM + 32768 + (size_t)cl * 16);
    }

#pragma unroll 1
    for (int i = 0; i < niter; i++) {
        const int curb = i & 1;
        __syncthreads();   // K(i),V(i) landed; all waves done with K(i-1),V(i-1)

        // prefetch K(i+1),V(i+1) into the other buffers (consumed next iter)
        if (i + 1 < niter) {
            int ktA = i + 1;
            int ktB = qt + 2 + i; if (ktB > 31) ktB = 31;   // defensive clamp
#pragma unroll
            for (int it = 0; it < 2; it++) {
                int cl = it * 512 + t;
                int ktile = (cl >> 9) ? ktB : ktA;
                async_copy16(Kg + (size_t)(ktile * 64 + cb_rr) * 64 + cb_kp * 32 + cb_cg * 8,
                             (char*)SMEM + (size_t)(curb ^ 1) * 16384 + (size_t)cl * 16);
                async_copy16(Vtg + (size_t)cb_rr * SEQ + ktile * 64 + cb_kp * 32 + cb_cg * 8,
                             (char*)SMEM + 32768 + (size_t)(curb ^ 1) * 16384 + (size_t)cl * 16);
            }
        }

        const int ktile = half ? (qt + 1 + i) : i;
        const bool active = (ktile * 64 <= qbase + 31);

        if (active) {
            const unsigned short* KsW = SMEM + curb * 8192 + half * 4096;  // ushort offs
            f32x4 st[4][2];
#pragma unroll
            for (int mt = 0; mt < 4; mt++)
#pragma unroll
                for (int ng = 0; ng < 2; ng++) st[mt][ng] = (f32x4){0.f, 0.f, 0.f, 0.f};
#pragma unroll
            for (int mt = 0; mt < 4; mt++)
#pragma unroll
                for (int kp = 0; kp < 2; kp++) {
                    bf16x8 ak = *(const bf16x8*)&KsW[kp * 2048 + (mt * 16 + r16) * 32 + swz * 8];
                    st[mt][0] = __builtin_amdgcn_mfma_f32_16x16x32_bf16(ak, bq[0][kp], st[mt][0], 0, 0, 0);
                    st[mt][1] = __builtin_amdgcn_mfma_f32_16x16x32_bf16(ak, bq[1][kp], st[mt][1], 0, 0, 0);
                }

            // causal mask (diagonal-straddling tiles only; wave-uniform branch)
            if (ktile * 64 + 63 > qbase) {
#pragma unroll
                for (int mt = 0; mt < 4; mt++) {
                    int kb = ktile * 64 + mt * 16 + quad * 4;
#pragma unroll
                    for (int ng = 0; ng < 2; ng++) {
                        int q = qbase + ng * 16 + r16;
#pragma unroll
                        for (int r = 0; r < 4; r++)
                            if (kb + r > q) st[mt][ng][r] = -__builtin_inff();
                    }
                }
            }

            // unshifted exp2 via raw v_exp_f32; st becomes P; m,z per lane
#pragma unroll
            for (int mt = 0; mt < 4; mt++)
#pragma unroll
                for (int ng = 0; ng < 2; ng++) {
                    float s0 = st[mt][ng][0], s1 = st[mt][ng][1];
                    float s2 = st[mt][ng][2], s3 = st[mt][ng][3];
                    m_run[ng] = fmaxf(m_run[ng], fmaxf(fmaxf(s0, s1), fmaxf(s2, s3)));
                    float p0 = fast_exp2(s0), p1 = fast_exp2(s1);
                    float p2 = fast_exp2(s2), p3 = fast_exp2(s3);
                    z_run[ng] += (p0 + p1) + (p2 + p3);
                    st[mt][ng][0] = p0; st[mt][ng][1] = p1;
                    st[mt][ng][2] = p2; st[mt][ng][3] = p3;
                }

            const unsigned short* VsW = SMEM + 16384 + curb * 8192 + half * 4096;
            // 4 phases: (k-half p) x (q-group ng): pack P into 1KB Ps, then PV.
#pragma unroll
            for (int p = 0; p < 2; p++) {
#pragma unroll
                for (int ng = 0; ng < 2; ng++) {
#pragma unroll
                    for (int ml = 0; ml < 2; ml++) {
                        int mt = p * 2 + ml;
                        ushort4 pk;
                        pk.x = bf16_bits(st[mt][ng][0]);
                        pk.y = bf16_bits(st[mt][ng][1]);
                        pk.z = bf16_bits(st[mt][ng][2]);
                        pk.w = bf16_bits(st[mt][ng][3]);
                        int c = (ml * 2 + (quad >> 1)) ^ pkey;
                        *(ushort4*)&PsW[r16 * 32 + c * 8 + (quad & 1) * 4] = pk;
                    }
                    bf16x8 bp = *(const bf16x8*)&PsW[r16 * 32 + (quad ^ pkey) * 8];
#pragma unroll
                    for (int mt = 0; mt < 4; mt++) {
                        bf16x8 av = *(const bf16x8*)&VsW[p * 2048 + (mt * 16 + r16) * 32 + swz * 8];
                        oT[mt][ng] = __builtin_amdgcn_mfma_f32_16x16x32_bf16(
                            av, bp, oT[mt][ng], 0, 0, 0);
                    }
                }
            }
        }
    }

    // fold per-lane m,z across quads
#pragma unroll
    for (int off = 16; off < 64; off <<= 1)
#pragma unroll
        for (int ng = 0; ng < 2; ng++) {
            m_run[ng] = fmaxf(m_run[ng], __shfl_xor(m_run[ng], off, 64));
            z_run[ng] += __shfl_xor(z_run[ng], off, 64);
        }

    // ---- combine k-halves through LDS (K/V and Ps regions dead) ----
    __syncthreads();
    f32x4* CbO = (f32x4*)SMEM;                        // 32KB
    f32x4* Ml = (f32x4*)((char*)SMEM + 32768);        // 4KB
    if (w >= 4) {
        int w4 = w - 4;
#pragma unroll
        for (int mt = 0; mt < 4; mt++)
#pragma unroll
            for (int ng = 0; ng < 2; ng++)
                CbO[((w4 * 8 + mt * 2 + ng) << 6) + lane] = oT[mt][ng];
        f32x4 ml;
        ml[0] = m_run[0]; ml[1] = m_run[1]; ml[2] = z_run[0]; ml[3] = z_run[1];
        Ml[(w4 << 6) + lane] = ml;
    }
    __syncthreads();
    if (w < 4) {
        f32x4 ml = Ml[(w << 6) + lane];
        float rd[2];
#pragma unroll
        for (int ng = 0; ng < 2; ng++) {
            float mtot = fmaxf(m_run[ng], ml[ng]);
            float ztot = z_run[ng] + ml[2 + ng];
            rd[ng] = 1.f / (fast_exp2(mtot) + ztot);  // quiet softmax denominator
        }
        const int b = bh >> 4, h = bh & 15;
#pragma unroll
        for (int mt = 0; mt < 4; mt++)
#pragma unroll
            for (int ng = 0; ng < 2; ng++) {
                f32x4 O1 = CbO[((w * 8 + mt * 2 + ng) << 6) + lane];
                int q = qbase + ng * 16 + r16;
                ushort4 pk;
                pk.x = bf16_bits((oT[mt][ng][0] + O1[0]) * rd[ng]);
                pk.y = bf16_bits((oT[mt][ng][1] + O1[1]) * rd[ng]);
                pk.z = bf16_bits((oT[mt][ng][2] + O1[2]) * rd[ng]);
                pk.w = bf16_bits((oT[mt][ng][3] + O1[3]) * rd[ng]);
                *(ushort4*)(ctxout + ((size_t)(b * SEQ + q)) * DIMN + h * 64 +
                            mt * 16 + quad * 4) = pk;
            }
    }
}

// ---------------- launch ----------------

extern "C" void kernel_launch(void* const* d_in, const int* in_sizes, int n_in,
                              void* d_out, int out_size, void* d_ws, size_t ws_size,
                              hipStream_t stream) {
    const float* x  = (const float*)d_in[0];
    const float* Wq = (const float*)d_in[1];
    const float* bq = (const float*)d_in[2];
    const float* Wk = (const float*)d_in[3];
    const float* bk = (const float*)d_in[4];
    const float* Wv = (const float*)d_in[5];
    const float* bv = (const float*)d_in[6];
    const float* Wo = (const float*)d_in[7];
    const float* bo = (const float*)d_in[8];

    char* ws = (char*)d_ws;
    __hip_bfloat16* xbf   = (__hip_bfloat16*)(ws);                           // 8 MB
    __hip_bfloat16* wqkvt = (__hip_bfloat16*)(ws + (8u << 20));              // 6 MB
    __hip_bfloat16* wot   = (__hip_bfloat16*)(ws + (14u << 20));             // 2 MB
    float*          biasq = (float*)(ws + (16u << 20));                      // 12 KB (pad 64K)
    __hip_bfloat16* qkv   = (__hip_bfloat16*)(ws + (16u << 20) + 65536u);    // 16 MB (Q,K)
    __hip_bfloat16* vt    = (__hip_bfloat16*)(ws + (16u << 20) + 65536u + (16u << 20)); // 8 MB
    __hip_bfloat16* ctx   = (__hip_bfloat16*)(ws + (16u << 20) + 65536u + (24u << 20)); // 8 MB
    float* out = (float*)d_out;

    prep_kernel<<<8195, 256, 0, stream>>>(x, bq, bk, bv, Wq, Wk, Wv, Wo,
                                          xbf, biasq, wqkvt, wot);
    gemm_qkv_kernel<<<dim3(16, 16), 1024, 0, stream>>>(xbf, wqkvt, biasq, qkv, vt);
    attn_mfma_kernel<<<512, 512, 0, stream>>>(qkv, vt, ctx);
    gemm_out_kernel<<<dim3(8, 64), 256, 0, stream>>>(ctx, wot, bo, out);
}